// Round 1
// baseline (646.580 us; speedup 1.0000x reference)
//
#include <hip/hip_runtime.h>
#include <math.h>

// GCN 5-layer: dims 16->64->128->256->512->1, N=20000 nodes, E=320000 edges.
// Plan: build CSR (by dst) once per launch, then per layer: fp32 tiled GEMM
// followed by gather-based aggregation (+mean+bias+relu). Final layer:
// wave-dot(512) + scalar aggregation + sigmoid.

#define N_NODES 20000
#define N_EDGES 320000

// ---------------- graph prep ----------------

__global__ void k_zero_int(int* p, int n) {
    int i = blockIdx.x * blockDim.x + threadIdx.x;
    if (i < n) p[i] = 0;
}

__global__ void k_count(const int* __restrict__ col, int* __restrict__ cnt, int E) {
    int e = blockIdx.x * blockDim.x + threadIdx.x;
    if (e < E) atomicAdd(&cnt[col[e]], 1);
}

__global__ void k_deg_dinv(const int* __restrict__ cnt, float* __restrict__ deg,
                           float* __restrict__ dinv, int n) {
    int v = blockIdx.x * blockDim.x + threadIdx.x;
    if (v < n) {
        float d = (float)(cnt[v] + 1);   // in-degree + self-loop
        deg[v] = d;
        dinv[v] = rsqrtf(d);
    }
}

// single-block exclusive scan over cnt[n] -> rowptr[n+1]; also copies into cursor[n]
__global__ void k_scan(const int* __restrict__ cnt, int* __restrict__ rowptr,
                       int* __restrict__ cursor, int n) {
    __shared__ int ssum[1024];
    int tid = threadIdx.x;                 // blockDim = 1024
    const int CH = (n + 1023) / 1024;      // elements per thread
    int begin = tid * CH;
    int local = 0;
    for (int i = 0; i < CH; i++) {
        int idx = begin + i;
        if (idx < n) local += cnt[idx];
    }
    ssum[tid] = local;
    __syncthreads();
    // Hillis-Steele inclusive scan over thread sums
    for (int off = 1; off < 1024; off <<= 1) {
        int v = ssum[tid];
        int add = (tid >= off) ? ssum[tid - off] : 0;
        __syncthreads();
        ssum[tid] = v + add;
        __syncthreads();
    }
    int run = (tid == 0) ? 0 : ssum[tid - 1];
    for (int i = 0; i < CH; i++) {
        int idx = begin + i;
        if (idx < n) {
            rowptr[idx] = run;
            cursor[idx] = run;
            run += cnt[idx];
        }
    }
    if (tid == 1023) rowptr[n] = ssum[1023];
}

__global__ void k_fill(const int* __restrict__ row, const int* __restrict__ col,
                       const float* __restrict__ dinv, int* __restrict__ cursor,
                       int* __restrict__ csr_src, float* __restrict__ csr_w, int E) {
    int e = blockIdx.x * blockDim.x + threadIdx.x;
    if (e >= E) return;
    int s = row[e], d = col[e];
    int pos = atomicAdd(&cursor[d], 1);
    csr_src[pos] = s;
    csr_w[pos] = dinv[s] * dinv[d];
}

// ---------------- GEMM: C[M,N] = A[M,K] @ B[K,N], fp32, 64x64 tile, 4x4/thread ----

#define BM 64
#define BN 64
#define BK 16

__global__ __launch_bounds__(256) void gemm64(const float* __restrict__ A,
                                              const float* __restrict__ B,
                                              float* __restrict__ C,
                                              int M, int K, int N) {
    __shared__ float As[BK][BM + 1];
    __shared__ float Bs[BK][BN + 1];
    int tid = threadIdx.y * 16 + threadIdx.x;   // 16x16 = 256 threads
    int block_row = blockIdx.y * BM;
    int block_col = blockIdx.x * BN;
    float acc[4][4] = {};
    for (int k0 = 0; k0 < K; k0 += BK) {
        // A tile: BM x BK (1024 elems, 4/thread), store transposed
        #pragma unroll
        for (int i = tid; i < BM * BK; i += 256) {
            int r = i / BK, c = i % BK;
            int gr = block_row + r;
            As[c][r] = (gr < M) ? A[(size_t)gr * K + k0 + c] : 0.0f;
        }
        // B tile: BK x BN
        #pragma unroll
        for (int i = tid; i < BK * BN; i += 256) {
            int r = i / BN, c = i % BN;
            Bs[r][c] = B[(size_t)(k0 + r) * N + block_col + c];
        }
        __syncthreads();
        #pragma unroll
        for (int kk = 0; kk < BK; kk++) {
            float a[4], b[4];
            #pragma unroll
            for (int i = 0; i < 4; i++) a[i] = As[kk][threadIdx.y * 4 + i];
            #pragma unroll
            for (int j = 0; j < 4; j++) b[j] = Bs[kk][threadIdx.x * 4 + j];
            #pragma unroll
            for (int i = 0; i < 4; i++)
                #pragma unroll
                for (int j = 0; j < 4; j++) acc[i][j] += a[i] * b[j];
        }
        __syncthreads();
    }
    #pragma unroll
    for (int i = 0; i < 4; i++) {
        int gr = block_row + threadIdx.y * 4 + i;
        if (gr < M) {
            #pragma unroll
            for (int j = 0; j < 4; j++)
                C[(size_t)gr * N + block_col + threadIdx.x * 4 + j] = acc[i][j];
        }
    }
}

// ---------------- aggregation: out[v,f] = relu((dinv[v]^2*h[v,f] + sum_e w_e*h[src_e,f])/deg[v] + b[f])

__global__ void k_aggregate(const float* __restrict__ h, float* __restrict__ out,
                            const int* __restrict__ rowptr, const int* __restrict__ csr_src,
                            const float* __restrict__ csr_w, const float* __restrict__ deg,
                            const float* __restrict__ dinv, const float* __restrict__ b,
                            int n, int d) {
    int v = blockIdx.x;
    int start = rowptr[v], end = rowptr[v + 1];
    float selfw = dinv[v] * dinv[v];
    float inv_cnt = 1.0f / deg[v];
    for (int f = threadIdx.x; f < d; f += blockDim.x) {
        float acc = selfw * h[(size_t)v * d + f];
        for (int e = start; e < end; e++) {
            int s = csr_src[e];
            acc += csr_w[e] * h[(size_t)s * d + f];
        }
        float r = acc * inv_cnt + b[f];
        out[(size_t)v * d + f] = fmaxf(r, 0.0f);
    }
}

// ---------------- final layer: dot(feat[v], W5) per node (wave reduce) ----------

__global__ void k_dot512(const float* __restrict__ A, const float* __restrict__ w,
                         float* __restrict__ out, int n, int K) {
    int wave = (blockIdx.x * blockDim.x + threadIdx.x) / 64;
    int lane = threadIdx.x & 63;
    if (wave >= n) return;
    float acc = 0.0f;
    for (int k = lane; k < K; k += 64) acc += A[(size_t)wave * K + k] * w[k];
    #pragma unroll
    for (int off = 32; off > 0; off >>= 1) acc += __shfl_down(acc, off, 64);
    if (lane == 0) out[wave] = acc;
}

__global__ void k_agg_final(const float* __restrict__ h, float* __restrict__ out,
                            const int* __restrict__ rowptr, const int* __restrict__ csr_src,
                            const float* __restrict__ csr_w, const float* __restrict__ dinv,
                            const float* __restrict__ b5, int n) {
    int v = blockIdx.x * blockDim.x + threadIdx.x;
    if (v >= n) return;
    float acc = dinv[v] * dinv[v] * h[v];
    int end = rowptr[v + 1];
    for (int e = rowptr[v]; e < end; e++) acc += csr_w[e] * h[csr_src[e]];
    float r = acc + b5[0];                 // 'add' aggregation, no mean
    out[v] = 1.0f / (1.0f + expf(-r));     // sigmoid
}

// ---------------- launch ----------------

extern "C" void kernel_launch(void* const* d_in, const int* in_sizes, int n_in,
                              void* d_out, int out_size, void* d_ws, size_t ws_size,
                              hipStream_t stream) {
    const float* x   = (const float*)d_in[0];
    const int*   ei  = (const int*)d_in[1];      // [2, E] int32
    const float* W[5] = {(const float*)d_in[2], (const float*)d_in[4], (const float*)d_in[6],
                         (const float*)d_in[8], (const float*)d_in[10]};
    const float* b[5] = {(const float*)d_in[3], (const float*)d_in[5], (const float*)d_in[7],
                         (const float*)d_in[9], (const float*)d_in[11]};
    const int n = in_sizes[0] / 16;              // 20000
    const int E = in_sizes[1] / 2;               // 320000
    const int dims[6] = {16, 64, 128, 256, 512, 1};

    const int* e_row = ei;          // src
    const int* e_col = ei + E;      // dst

    // workspace layout (floats/ints, all 4B-aligned; padded to 16B boundaries)
    float* bufA   = (float*)d_ws;                     // n*512
    float* bufB   = bufA + (size_t)n * 512;           // n*512
    int*   cnt    = (int*)(bufB + (size_t)n * 512);   // n
    int*   rowptr = cnt + n;                          // n+1 (pad to n+4)
    int*   cursor = rowptr + n + 4;                   // n
    float* deg    = (float*)(cursor + n);             // n
    float* dinv   = deg + n;                          // n
    int*   csr_src= (int*)(dinv + n);                 // E
    float* csr_w  = (float*)(csr_src + E);            // E

    // ---- graph prep ----
    k_zero_int<<<(n + 255) / 256, 256, 0, stream>>>(cnt, n);
    k_count<<<(E + 255) / 256, 256, 0, stream>>>(e_col, cnt, E);
    k_deg_dinv<<<(n + 255) / 256, 256, 0, stream>>>(cnt, deg, dinv, n);
    k_scan<<<1, 1024, 0, stream>>>(cnt, rowptr, cursor, n);
    k_fill<<<(E + 255) / 256, 256, 0, stream>>>(e_row, e_col, dinv, cursor, csr_src, csr_w, E);

    // ---- layers 1..4: GEMM -> aggregate(mean)+bias+relu ----
    const float* in_feat = x;
    for (int l = 0; l < 4; l++) {
        int K = dims[l], M = n, Nd = dims[l + 1];
        dim3 ggrid(Nd / BN, (M + BM - 1) / BM);
        dim3 gblk(16, 16);
        gemm64<<<ggrid, gblk, 0, stream>>>(in_feat, W[l], bufB, M, K, Nd);
        int bthreads = (Nd >= 256) ? 256 : Nd;   // 64 / 128 / 256
        k_aggregate<<<n, bthreads, 0, stream>>>(bufB, bufA, rowptr, csr_src, csr_w,
                                                deg, dinv, b[l], n, Nd);
        in_feat = bufA;
    }

    // ---- layer 5: dot + add-aggregate + sigmoid ----
    k_dot512<<<(n * 64 + 255) / 256, 256, 0, stream>>>(bufA, W[4], bufB, n, 512);
    k_agg_final<<<(n + 255) / 256, 256, 0, stream>>>(bufB, (float*)d_out, rowptr,
                                                     csr_src, csr_w, dinv, b[4], n);
}

// Round 2
// 473.474 us; speedup vs baseline: 1.3656x; 1.3656x over previous
//
#include <hip/hip_runtime.h>
#include <math.h>

// GCN 5-layer: dims 16->64->128->256->512->1, N=20000, E=320000.
// Round 1: aggregate BEFORE the GEMM (aggregation commutes with W), at the
// layer's input dim (16/64/128/256 instead of 64/128/256/512) -> 2.07x less
// gather traffic. float4-vectorized group-per-node aggregation; bias+ReLU
// fused into GEMM epilogue.

#define N_NODES 20000
#define N_EDGES 320000

// ---------------- graph prep ----------------

__global__ void k_zero_int(int* p, int n) {
    int i = blockIdx.x * blockDim.x + threadIdx.x;
    if (i < n) p[i] = 0;
}

__global__ void k_count(const int* __restrict__ col, int* __restrict__ cnt, int E) {
    int e = blockIdx.x * blockDim.x + threadIdx.x;
    if (e < E) atomicAdd(&cnt[col[e]], 1);
}

__global__ void k_deg_dinv(const int* __restrict__ cnt, float* __restrict__ deg,
                           float* __restrict__ dinv, int n) {
    int v = blockIdx.x * blockDim.x + threadIdx.x;
    if (v < n) {
        float d = (float)(cnt[v] + 1);   // in-degree + self-loop
        deg[v] = d;
        dinv[v] = rsqrtf(d);
    }
}

// single-block exclusive scan over cnt[n] -> rowptr[n+1]; also fills cursor[n]
__global__ void k_scan(const int* __restrict__ cnt, int* __restrict__ rowptr,
                       int* __restrict__ cursor, int n) {
    __shared__ int ssum[1024];
    int tid = threadIdx.x;                 // blockDim = 1024
    const int CH = (n + 1023) / 1024;
    int begin = tid * CH;
    int local = 0;
    for (int i = 0; i < CH; i++) {
        int idx = begin + i;
        if (idx < n) local += cnt[idx];
    }
    ssum[tid] = local;
    __syncthreads();
    for (int off = 1; off < 1024; off <<= 1) {
        int v = ssum[tid];
        int add = (tid >= off) ? ssum[tid - off] : 0;
        __syncthreads();
        ssum[tid] = v + add;
        __syncthreads();
    }
    int run = (tid == 0) ? 0 : ssum[tid - 1];
    for (int i = 0; i < CH; i++) {
        int idx = begin + i;
        if (idx < n) {
            rowptr[idx] = run;
            cursor[idx] = run;
            run += cnt[idx];
        }
    }
    if (tid == 1023) rowptr[n] = ssum[1023];
}

__global__ void k_fill(const int* __restrict__ row, const int* __restrict__ col,
                       const float* __restrict__ dinv, int* __restrict__ cursor,
                       int* __restrict__ csr_src, float* __restrict__ csr_w, int E) {
    int e = blockIdx.x * blockDim.x + threadIdx.x;
    if (e >= E) return;
    int s = row[e], d = col[e];
    int pos = atomicAdd(&cursor[d], 1);
    csr_src[pos] = s;
    csr_w[pos] = dinv[s] * dinv[d];
}

// ---------------- pre-aggregation (float4, group-per-node) ----------------
// out[v,:] = (dinv[v]^2 * h[v,:] + sum_e w_e * h[src_e,:]) / deg[v]
// d floats per node = g = d/4 float4's; one group of g threads per node.

__global__ void k_agg_pre(const float4* __restrict__ h, float4* __restrict__ out,
                          const int* __restrict__ rowptr, const int* __restrict__ csr_src,
                          const float* __restrict__ csr_w, const float* __restrict__ deg,
                          const float* __restrict__ dinv, int n, int g_shift) {
    int g = 1 << g_shift;                        // threads per node (= d/4)
    int grp = threadIdx.x >> g_shift;
    int lane = threadIdx.x & (g - 1);
    int gpb = blockDim.x >> g_shift;             // nodes per block
    int v = blockIdx.x * gpb + grp;
    if (v >= n) return;
    float dv = dinv[v];
    float selfw = dv * dv;
    float inv_cnt = 1.0f / deg[v];
    int start = rowptr[v], end = rowptr[v + 1];
    float4 hv = h[(size_t)v * g + lane];
    float4 acc = make_float4(selfw * hv.x, selfw * hv.y, selfw * hv.z, selfw * hv.w);
    for (int e = start; e < end; e++) {
        int s = csr_src[e];
        float w = csr_w[e];
        float4 hs = h[(size_t)s * g + lane];
        acc.x += w * hs.x; acc.y += w * hs.y; acc.z += w * hs.z; acc.w += w * hs.w;
    }
    out[(size_t)v * g + lane] =
        make_float4(acc.x * inv_cnt, acc.y * inv_cnt, acc.z * inv_cnt, acc.w * inv_cnt);
}

// ---------------- GEMM: C = relu?(A @ B + bias), fp32, 64x64 tile, 4x4/thread ----

#define BM 64
#define BN 64
#define BK 16

__global__ __launch_bounds__(256) void gemm64(const float* __restrict__ A,
                                              const float* __restrict__ B,
                                              const float* __restrict__ bias,
                                              float* __restrict__ C,
                                              int M, int K, int N, int do_relu) {
    __shared__ float As[BK][BM + 1];
    __shared__ float Bs[BK][BN + 1];
    int tid = threadIdx.y * 16 + threadIdx.x;
    int block_row = blockIdx.y * BM;
    int block_col = blockIdx.x * BN;
    float acc[4][4] = {};
    for (int k0 = 0; k0 < K; k0 += BK) {
        #pragma unroll
        for (int i = tid; i < BM * BK; i += 256) {
            int r = i / BK, c = i % BK;
            int gr = block_row + r;
            As[c][r] = (gr < M) ? A[(size_t)gr * K + k0 + c] : 0.0f;
        }
        #pragma unroll
        for (int i = tid; i < BK * BN; i += 256) {
            int r = i / BN, c = i % BN;
            Bs[r][c] = B[(size_t)(k0 + r) * N + block_col + c];
        }
        __syncthreads();
        #pragma unroll
        for (int kk = 0; kk < BK; kk++) {
            float a[4], b[4];
            #pragma unroll
            for (int i = 0; i < 4; i++) a[i] = As[kk][threadIdx.y * 4 + i];
            #pragma unroll
            for (int j = 0; j < 4; j++) b[j] = Bs[kk][threadIdx.x * 4 + j];
            #pragma unroll
            for (int i = 0; i < 4; i++)
                #pragma unroll
                for (int j = 0; j < 4; j++) acc[i][j] += a[i] * b[j];
        }
        __syncthreads();
    }
    float bj[4];
    #pragma unroll
    for (int j = 0; j < 4; j++) bj[j] = bias[block_col + threadIdx.x * 4 + j];
    #pragma unroll
    for (int i = 0; i < 4; i++) {
        int gr = block_row + threadIdx.y * 4 + i;
        if (gr < M) {
            #pragma unroll
            for (int j = 0; j < 4; j++) {
                float r = acc[i][j] + bj[j];
                if (do_relu) r = fmaxf(r, 0.0f);
                C[(size_t)gr * N + block_col + threadIdx.x * 4 + j] = r;
            }
        }
    }
}

// ---------------- final layer ----------------

__global__ void k_dot512(const float* __restrict__ A, const float* __restrict__ w,
                         float* __restrict__ out, int n, int K) {
    int wave = (blockIdx.x * blockDim.x + threadIdx.x) / 64;
    int lane = threadIdx.x & 63;
    if (wave >= n) return;
    float acc = 0.0f;
    for (int k = lane; k < K; k += 64) acc += A[(size_t)wave * K + k] * w[k];
    #pragma unroll
    for (int off = 32; off > 0; off >>= 1) acc += __shfl_down(acc, off, 64);
    if (lane == 0) out[wave] = acc;
}

__global__ void k_agg_final(const float* __restrict__ h, float* __restrict__ out,
                            const int* __restrict__ rowptr, const int* __restrict__ csr_src,
                            const float* __restrict__ csr_w, const float* __restrict__ dinv,
                            const float* __restrict__ b5, int n) {
    int v = blockIdx.x * blockDim.x + threadIdx.x;
    if (v >= n) return;
    float acc = dinv[v] * dinv[v] * h[v];
    int end = rowptr[v + 1];
    for (int e = rowptr[v]; e < end; e++) acc += csr_w[e] * h[csr_src[e]];
    float r = acc + b5[0];                 // 'add' aggregation (output layer)
    out[v] = 1.0f / (1.0f + expf(-r));     // sigmoid
}

// ---------------- launch ----------------

extern "C" void kernel_launch(void* const* d_in, const int* in_sizes, int n_in,
                              void* d_out, int out_size, void* d_ws, size_t ws_size,
                              hipStream_t stream) {
    const float* x   = (const float*)d_in[0];
    const int*   ei  = (const int*)d_in[1];
    const float* W[5] = {(const float*)d_in[2], (const float*)d_in[4], (const float*)d_in[6],
                         (const float*)d_in[8], (const float*)d_in[10]};
    const float* b[5] = {(const float*)d_in[3], (const float*)d_in[5], (const float*)d_in[7],
                         (const float*)d_in[9], (const float*)d_in[11]};
    const int n = in_sizes[0] / 16;
    const int E = in_sizes[1] / 2;
    const int dims[6] = {16, 64, 128, 256, 512, 1};

    const int* e_row = ei;          // src
    const int* e_col = ei + E;      // dst

    // workspace layout
    float* bufA   = (float*)d_ws;                     // n*512
    float* bufB   = bufA + (size_t)n * 512;           // n*512
    int*   cnt    = (int*)(bufB + (size_t)n * 512);   // n
    int*   rowptr = cnt + n;                          // n+1 (pad to n+4)
    int*   cursor = rowptr + n + 4;                   // n
    float* deg    = (float*)(cursor + n);             // n
    float* dinv   = deg + n;                          // n
    int*   csr_src= (int*)(dinv + n);                 // E
    float* csr_w  = (float*)(csr_src + E);            // E

    // ---- graph prep ----
    k_zero_int<<<(n + 255) / 256, 256, 0, stream>>>(cnt, n);
    k_count<<<(E + 255) / 256, 256, 0, stream>>>(e_col, cnt, E);
    k_deg_dinv<<<(n + 255) / 256, 256, 0, stream>>>(cnt, deg, dinv, n);
    k_scan<<<1, 1024, 0, stream>>>(cnt, rowptr, cursor, n);
    k_fill<<<(E + 255) / 256, 256, 0, stream>>>(e_row, e_col, dinv, cursor, csr_src, csr_w, E);

    // ---- layers 1..4: aggregate(mean) at d_in -> GEMM(+bias+relu) ----
    const float* in_feat = x;
    for (int l = 0; l < 4; l++) {
        int K = dims[l], M = n, Nd = dims[l + 1];
        // pre-aggregate at input dim K: g = K/4 threads per node
        int g_shift = (K == 16) ? 2 : (K == 64) ? 4 : (K == 128) ? 5 : 6;
        int gpb = 256 >> g_shift;                    // nodes per 256-thread block
        int agrid = (n + gpb - 1) / gpb;
        k_agg_pre<<<agrid, 256, 0, stream>>>((const float4*)in_feat, (float4*)bufB,
                                             rowptr, csr_src, csr_w, deg, dinv, n, g_shift);
        dim3 ggrid(Nd / BN, (M + BM - 1) / BM);
        dim3 gblk(16, 16);
        gemm64<<<ggrid, gblk, 0, stream>>>(bufB, W[l], b[l], bufA, M, K, Nd, 1);
        in_feat = bufA;
    }

    // ---- layer 5: dot + add-aggregate + sigmoid ----
    k_dot512<<<(n * 64 + 255) / 256, 256, 0, stream>>>(bufA, W[4], bufB, n, 512);
    k_agg_final<<<(n + 255) / 256, 256, 0, stream>>>(bufB, (float*)d_out, rowptr,
                                                     csr_src, csr_w, dinv, b[4], n);
}

// Round 3
// 360.310 us; speedup vs baseline: 1.7945x; 1.3141x over previous
//
#include <hip/hip_runtime.h>
#include <hip/hip_bf16.h>
#include <math.h>

// GCN 5-layer: dims 16->64->128->256->512->1, N=20000, E=320000.
// Round 2: replace fp32 vector GEMM with bf16 MFMA GEMM (16x16x32, 128x128
// tile, gemm-BT pattern with pre-transposed bf16 weights). Aggregation
// (fp32 gather/accumulate) now writes bf16 A directly; bias+ReLU fused in
// fp32 GEMM epilogue.

#define N_NODES 20000
#define N_EDGES 320000

typedef __attribute__((ext_vector_type(8))) short short8;
typedef __attribute__((ext_vector_type(4))) float f32x4;

__device__ inline ushort f2bf(float f) {
    __hip_bfloat16 h = __float2bfloat16(f);   // RNE
    return *(ushort*)&h;
}

// ---------------- graph prep ----------------

__global__ void k_zero_int(int* p, int n) {
    int i = blockIdx.x * blockDim.x + threadIdx.x;
    if (i < n) p[i] = 0;
}

__global__ void k_count(const int* __restrict__ col, int* __restrict__ cnt, int E) {
    int e = blockIdx.x * blockDim.x + threadIdx.x;
    if (e < E) atomicAdd(&cnt[col[e]], 1);
}

__global__ void k_deg_dinv(const int* __restrict__ cnt, float* __restrict__ deg,
                           float* __restrict__ dinv, int n) {
    int v = blockIdx.x * blockDim.x + threadIdx.x;
    if (v < n) {
        float d = (float)(cnt[v] + 1);   // in-degree + self-loop
        deg[v] = d;
        dinv[v] = rsqrtf(d);
    }
}

__global__ void k_scan(const int* __restrict__ cnt, int* __restrict__ rowptr,
                       int* __restrict__ cursor, int n) {
    __shared__ int ssum[1024];
    int tid = threadIdx.x;                 // blockDim = 1024
    const int CH = (n + 1023) / 1024;
    int begin = tid * CH;
    int local = 0;
    for (int i = 0; i < CH; i++) {
        int idx = begin + i;
        if (idx < n) local += cnt[idx];
    }
    ssum[tid] = local;
    __syncthreads();
    for (int off = 1; off < 1024; off <<= 1) {
        int v = ssum[tid];
        int add = (tid >= off) ? ssum[tid - off] : 0;
        __syncthreads();
        ssum[tid] = v + add;
        __syncthreads();
    }
    int run = (tid == 0) ? 0 : ssum[tid - 1];
    for (int i = 0; i < CH; i++) {
        int idx = begin + i;
        if (idx < n) {
            rowptr[idx] = run;
            cursor[idx] = run;
            run += cnt[idx];
        }
    }
    if (tid == 1023) rowptr[n] = ssum[1023];
}

__global__ void k_fill(const int* __restrict__ row, const int* __restrict__ col,
                       const float* __restrict__ dinv, int* __restrict__ cursor,
                       int* __restrict__ csr_src, float* __restrict__ csr_w, int E) {
    int e = blockIdx.x * blockDim.x + threadIdx.x;
    if (e >= E) return;
    int s = row[e], d = col[e];
    int pos = atomicAdd(&cursor[d], 1);
    csr_src[pos] = s;
    csr_w[pos] = dinv[s] * dinv[d];
}

// ---------------- pre-aggregation (fp32 gather -> bf16 write) ----------------
// out[v,:] = bf16( (dinv[v]^2 * h[v,:] + sum_e w_e * h[src_e,:]) / deg[v] )

__global__ void k_agg_pre(const float4* __restrict__ h, ushort4* __restrict__ out,
                          const int* __restrict__ rowptr, const int* __restrict__ csr_src,
                          const float* __restrict__ csr_w, const float* __restrict__ deg,
                          const float* __restrict__ dinv, int n, int g_shift) {
    int g = 1 << g_shift;                        // threads per node (= d/4)
    int grp = threadIdx.x >> g_shift;
    int lane = threadIdx.x & (g - 1);
    int gpb = blockDim.x >> g_shift;             // nodes per block
    int v = blockIdx.x * gpb + grp;
    if (v >= n) return;
    float dv = dinv[v];
    float selfw = dv * dv;
    float inv_cnt = 1.0f / deg[v];
    int start = rowptr[v], end = rowptr[v + 1];
    float4 hv = h[(size_t)v * g + lane];
    float4 acc = make_float4(selfw * hv.x, selfw * hv.y, selfw * hv.z, selfw * hv.w);
    for (int e = start; e < end; e++) {
        int s = csr_src[e];
        float w = csr_w[e];
        float4 hs = h[(size_t)s * g + lane];
        acc.x += w * hs.x; acc.y += w * hs.y; acc.z += w * hs.z; acc.w += w * hs.w;
    }
    ushort4 o;
    o.x = f2bf(acc.x * inv_cnt);
    o.y = f2bf(acc.y * inv_cnt);
    o.z = f2bf(acc.z * inv_cnt);
    o.w = f2bf(acc.w * inv_cnt);
    out[(size_t)v * g + lane] = o;
}

// ---------------- weight transpose+convert: Wt[n][k] = bf16(W[k][n]) --------

__global__ void k_wt(const float* __restrict__ W, ushort* __restrict__ Wt, int K, int N) {
    int i = blockIdx.x * blockDim.x + threadIdx.x;
    if (i >= N * K) return;
    int nn = i / K, kk = i % K;
    Wt[i] = f2bf(W[(size_t)kk * N + nn]);
}

// ---------------- MFMA GEMM: C[M,N] = relu(A[M,K] @ Wt[N,K]^T + bias) -------
// bf16 inputs, fp32 accumulate. 128x128 tile, 4 waves (2x2), each wave 64x64
// as 4x4 grid of 16x16x32 MFMAs.

#define GBM 128
#define GBN 128
#define GBK 32
#define LDSS 40   // LDS row stride in elements (80B, 16B-aligned)

__global__ __launch_bounds__(256) void gemm_mfma(const ushort* __restrict__ A,
                                                 const ushort* __restrict__ Wt,
                                                 const float* __restrict__ bias,
                                                 float* __restrict__ C,
                                                 int M, int K, int N, int do_relu) {
    __shared__ ushort As[GBM * LDSS];
    __shared__ ushort Bs[GBN * LDSS];
    int tid = threadIdx.x;
    int wave = tid >> 6;
    int lane = tid & 63;
    int wr = wave >> 1, wc = wave & 1;
    int q = lane >> 4;          // quad 0..3
    int mr = lane & 15;
    int row0 = blockIdx.y * GBM;
    int col0 = blockIdx.x * GBN;

    f32x4 acc[4][4];
    #pragma unroll
    for (int i = 0; i < 4; i++)
        #pragma unroll
        for (int j = 0; j < 4; j++) acc[i][j] = (f32x4){0.f, 0.f, 0.f, 0.f};

    const short8 zero8 = {0, 0, 0, 0, 0, 0, 0, 0};

    for (int k0 = 0; k0 < K; k0 += GBK) {
        // stage A and B tiles: 128 rows x 32 cols each, 8 bf16 per thread x2
        #pragma unroll
        for (int it = 0; it < 2; it++) {
            int t = tid + it * 256;
            int r = t >> 2;               // row in tile (0..127)
            int koff = (t & 3) * 8;       // k offset in tile
            int gk = k0 + koff;
            short8 va = zero8;
            int gr = row0 + r;
            if (gr < M && gk < K)
                va = *(const short8*)(A + (size_t)gr * K + gk);
            *(short8*)(As + r * LDSS + koff) = va;
            short8 vb = zero8;
            int gn = col0 + r;
            if (gn < N && gk < K)
                vb = *(const short8*)(Wt + (size_t)gn * K + gk);
            *(short8*)(Bs + r * LDSS + koff) = vb;
        }
        __syncthreads();
        short8 afr[4], bfr[4];
        #pragma unroll
        for (int i = 0; i < 4; i++)
            afr[i] = *(const short8*)(As + (wr * 64 + i * 16 + mr) * LDSS + q * 8);
        #pragma unroll
        for (int j = 0; j < 4; j++)
            bfr[j] = *(const short8*)(Bs + (wc * 64 + j * 16 + mr) * LDSS + q * 8);
        #pragma unroll
        for (int i = 0; i < 4; i++)
            #pragma unroll
            for (int j = 0; j < 4; j++)
                acc[i][j] = __builtin_amdgcn_mfma_f32_16x16x32_bf16(afr[i], bfr[j],
                                                                    acc[i][j], 0, 0, 0);
        __syncthreads();
    }

    // epilogue: C/D layout col=lane&15, row=q*4+reg
    #pragma unroll
    for (int j = 0; j < 4; j++) {
        int col = col0 + wc * 64 + j * 16 + mr;
        if (col >= N) continue;
        float bj = bias[col];
        #pragma unroll
        for (int i = 0; i < 4; i++) {
            int rbase = row0 + wr * 64 + i * 16 + q * 4;
            #pragma unroll
            for (int r = 0; r < 4; r++) {
                int grow = rbase + r;
                if (grow < M) {
                    float v = acc[i][j][r] + bj;
                    if (do_relu) v = fmaxf(v, 0.0f);
                    C[(size_t)grow * N + col] = v;
                }
            }
        }
    }
}

// ---------------- final layer ----------------

__global__ void k_dot512(const float* __restrict__ A, const float* __restrict__ w,
                         float* __restrict__ out, int n, int K) {
    int wave = (blockIdx.x * blockDim.x + threadIdx.x) / 64;
    int lane = threadIdx.x & 63;
    if (wave >= n) return;
    float acc = 0.0f;
    for (int k = lane; k < K; k += 64) acc += A[(size_t)wave * K + k] * w[k];
    #pragma unroll
    for (int off = 32; off > 0; off >>= 1) acc += __shfl_down(acc, off, 64);
    if (lane == 0) out[wave] = acc;
}

__global__ void k_agg_final(const float* __restrict__ h, float* __restrict__ out,
                            const int* __restrict__ rowptr, const int* __restrict__ csr_src,
                            const float* __restrict__ csr_w, const float* __restrict__ dinv,
                            const float* __restrict__ b5, int n) {
    int v = blockIdx.x * blockDim.x + threadIdx.x;
    if (v >= n) return;
    float acc = dinv[v] * dinv[v] * h[v];
    int end = rowptr[v + 1];
    for (int e = rowptr[v]; e < end; e++) acc += csr_w[e] * h[csr_src[e]];
    float r = acc + b5[0];                 // 'add' aggregation (output layer)
    out[v] = 1.0f / (1.0f + expf(-r));     // sigmoid
}

// ---------------- launch ----------------

extern "C" void kernel_launch(void* const* d_in, const int* in_sizes, int n_in,
                              void* d_out, int out_size, void* d_ws, size_t ws_size,
                              hipStream_t stream) {
    const float* x   = (const float*)d_in[0];
    const int*   ei  = (const int*)d_in[1];
    const float* W[5] = {(const float*)d_in[2], (const float*)d_in[4], (const float*)d_in[6],
                         (const float*)d_in[8], (const float*)d_in[10]};
    const float* b[5] = {(const float*)d_in[3], (const float*)d_in[5], (const float*)d_in[7],
                         (const float*)d_in[9], (const float*)d_in[11]};
    const int n = in_sizes[0] / 16;
    const int E = in_sizes[1] / 2;
    const int dims[6] = {16, 64, 128, 256, 512, 1};

    const int* e_row = ei;          // src
    const int* e_col = ei + E;      // dst

    // workspace layout
    float* bufA   = (float*)d_ws;                     // n*512 fp32 (GEMM out)
    float* bufB   = bufA + (size_t)n * 512;           // n*512 region (bf16 agg out / fp32 dot out)
    int*   cnt    = (int*)(bufB + (size_t)n * 512);   // n
    int*   rowptr = cnt + n;                          // n+1 (pad to n+4)
    int*   cursor = rowptr + n + 4;                   // n
    float* deg    = (float*)(cursor + n);             // n
    float* dinv   = deg + n;                          // n
    int*   csr_src= (int*)(dinv + n);                 // E
    float* csr_w  = (float*)(csr_src + E);            // E
    ushort* wt0   = (ushort*)(csr_w + E);             // bf16 transposed weights:
    ushort* wt1   = wt0 + 16 * 64;                    //  16*64 + 64*128 + 128*256 + 256*512
    ushort* wt2   = wt1 + 64 * 128;
    ushort* wt3   = wt2 + 128 * 256;
    ushort* wts[4] = {wt0, wt1, wt2, wt3};

    // ---- graph prep ----
    k_zero_int<<<(n + 255) / 256, 256, 0, stream>>>(cnt, n);
    k_count<<<(E + 255) / 256, 256, 0, stream>>>(e_col, cnt, E);
    k_deg_dinv<<<(n + 255) / 256, 256, 0, stream>>>(cnt, deg, dinv, n);
    k_scan<<<1, 1024, 0, stream>>>(cnt, rowptr, cursor, n);
    k_fill<<<(E + 255) / 256, 256, 0, stream>>>(e_row, e_col, dinv, cursor, csr_src, csr_w, E);

    // ---- weight transpose/convert ----
    for (int l = 0; l < 4; l++) {
        int K = dims[l], Nd = dims[l + 1];
        k_wt<<<(K * Nd + 255) / 256, 256, 0, stream>>>(W[l], wts[l], K, Nd);
    }

    // ---- layers 1..4: aggregate(mean, ->bf16) -> MFMA GEMM(+bias+relu) ----
    const float* in_feat = x;
    for (int l = 0; l < 4; l++) {
        int K = dims[l], M = n, Nd = dims[l + 1];
        int g_shift = (K == 16) ? 2 : (K == 64) ? 4 : (K == 128) ? 5 : 6;
        int gpb = 256 >> g_shift;
        int agrid = (n + gpb - 1) / gpb;
        k_agg_pre<<<agrid, 256, 0, stream>>>((const float4*)in_feat, (ushort4*)bufB,
                                             rowptr, csr_src, csr_w, deg, dinv, n, g_shift);
        dim3 ggrid((Nd + GBN - 1) / GBN, (M + GBM - 1) / GBM);
        gemm_mfma<<<ggrid, 256, 0, stream>>>((const ushort*)bufB, wts[l], b[l], bufA,
                                             M, K, Nd, 1);
        in_feat = bufA;
    }

    // ---- layer 5: dot + add-aggregate + sigmoid ----
    k_dot512<<<(n * 64 + 255) / 256, 256, 0, stream>>>(bufA, W[4], bufB, n, 512);
    k_agg_final<<<(n + 255) / 256, 256, 0, stream>>>(bufB, (float*)d_out, rowptr,
                                                     csr_src, csr_w, dinv, b[4], n);
}

// Round 4
// 308.702 us; speedup vs baseline: 2.0945x; 1.1672x over previous
//
#include <hip/hip_runtime.h>
#include <hip/hip_bf16.h>
#include <math.h>

// GCN 5-layer: dims 16->64->128->256->512->1, N=20000, E=320000.
// Round 3: activations h stored bf16 end-to-end. GEMM epilogue emits bf16;
// aggregation gathers bf16 (ushort8 16B loads, fp32 accumulate, bf16 write);
// layer-5 dot reads bf16 in one shot. Halves all gather/write traffic vs r2.

#define N_NODES 20000
#define N_EDGES 320000

typedef __attribute__((ext_vector_type(8))) short short8;
typedef __attribute__((ext_vector_type(4))) float f32x4;

__device__ inline ushort f2bf(float f) {
    __hip_bfloat16 h = __float2bfloat16(f);   // RNE
    return *(ushort*)&h;
}

__device__ inline float bf2f(short s) {
    union { unsigned int u; float f; } c;
    c.u = ((unsigned int)(unsigned short)s) << 16;
    return c.f;
}

// ---------------- graph prep ----------------

__global__ void k_zero_int(int* p, int n) {
    int i = blockIdx.x * blockDim.x + threadIdx.x;
    if (i < n) p[i] = 0;
}

__global__ void k_count(const int* __restrict__ col, int* __restrict__ cnt, int E) {
    int e = blockIdx.x * blockDim.x + threadIdx.x;
    if (e < E) atomicAdd(&cnt[col[e]], 1);
}

__global__ void k_deg_dinv(const int* __restrict__ cnt, float* __restrict__ deg,
                           float* __restrict__ dinv, int n) {
    int v = blockIdx.x * blockDim.x + threadIdx.x;
    if (v < n) {
        float d = (float)(cnt[v] + 1);   // in-degree + self-loop
        deg[v] = d;
        dinv[v] = rsqrtf(d);
    }
}

__global__ void k_scan(const int* __restrict__ cnt, int* __restrict__ rowptr,
                       int* __restrict__ cursor, int n) {
    __shared__ int ssum[1024];
    int tid = threadIdx.x;                 // blockDim = 1024
    const int CH = (n + 1023) / 1024;
    int begin = tid * CH;
    int local = 0;
    for (int i = 0; i < CH; i++) {
        int idx = begin + i;
        if (idx < n) local += cnt[idx];
    }
    ssum[tid] = local;
    __syncthreads();
    for (int off = 1; off < 1024; off <<= 1) {
        int v = ssum[tid];
        int add = (tid >= off) ? ssum[tid - off] : 0;
        __syncthreads();
        ssum[tid] = v + add;
        __syncthreads();
    }
    int run = (tid == 0) ? 0 : ssum[tid - 1];
    for (int i = 0; i < CH; i++) {
        int idx = begin + i;
        if (idx < n) {
            rowptr[idx] = run;
            cursor[idx] = run;
            run += cnt[idx];
        }
    }
    if (tid == 1023) rowptr[n] = ssum[1023];
}

__global__ void k_fill(const int* __restrict__ row, const int* __restrict__ col,
                       const float* __restrict__ dinv, int* __restrict__ cursor,
                       int* __restrict__ csr_src, float* __restrict__ csr_w, int E) {
    int e = blockIdx.x * blockDim.x + threadIdx.x;
    if (e >= E) return;
    int s = row[e], d = col[e];
    int pos = atomicAdd(&cursor[d], 1);
    csr_src[pos] = s;
    csr_w[pos] = dinv[s] * dinv[d];
}

// ---------------- layer-1 pre-aggregation (fp32 x -> bf16 out), d=16 --------

__global__ void k_agg_pre_f32(const float4* __restrict__ h, ushort4* __restrict__ out,
                              const int* __restrict__ rowptr, const int* __restrict__ csr_src,
                              const float* __restrict__ csr_w, const float* __restrict__ deg,
                              const float* __restrict__ dinv, int n) {
    const int g_shift = 2;                       // d=16 -> 4 float4 lanes per node
    int g = 1 << g_shift;
    int grp = threadIdx.x >> g_shift;
    int lane = threadIdx.x & (g - 1);
    int gpb = blockDim.x >> g_shift;
    int v = blockIdx.x * gpb + grp;
    if (v >= n) return;
    float dv = dinv[v];
    float selfw = dv * dv;
    float inv_cnt = 1.0f / deg[v];
    int start = rowptr[v], end = rowptr[v + 1];
    float4 hv = h[(size_t)v * g + lane];
    float4 acc = make_float4(selfw * hv.x, selfw * hv.y, selfw * hv.z, selfw * hv.w);
    for (int e = start; e < end; e++) {
        int s = csr_src[e];
        float w = csr_w[e];
        float4 hs = h[(size_t)s * g + lane];
        acc.x += w * hs.x; acc.y += w * hs.y; acc.z += w * hs.z; acc.w += w * hs.w;
    }
    ushort4 o;
    o.x = f2bf(acc.x * inv_cnt);
    o.y = f2bf(acc.y * inv_cnt);
    o.z = f2bf(acc.z * inv_cnt);
    o.w = f2bf(acc.w * inv_cnt);
    out[(size_t)v * g + lane] = o;
}

// ---------------- bf16 pre-aggregation (layers 2..4) ------------------------
// out[v,:] = bf16( (dinv^2 h[v,:] + sum_e w_e h[src_e,:]) / deg[v] ), h bf16.
// g = d/8 lanes per node, each lane owns 8 features (one short8 / 16B).

__global__ void k_agg_pre_bf16(const short8* __restrict__ h, short8* __restrict__ out,
                               const int* __restrict__ rowptr, const int* __restrict__ csr_src,
                               const float* __restrict__ csr_w, const float* __restrict__ deg,
                               const float* __restrict__ dinv, int n, int g_shift) {
    int g = 1 << g_shift;                        // lanes per node = d/8
    int grp = threadIdx.x >> g_shift;
    int lane = threadIdx.x & (g - 1);
    int gpb = blockDim.x >> g_shift;
    int v = blockIdx.x * gpb + grp;
    if (v >= n) return;
    float dv = dinv[v];
    float selfw = dv * dv;
    float inv_cnt = 1.0f / deg[v];
    int start = rowptr[v], end = rowptr[v + 1];

    float acc[8];
    short8 hv = h[(size_t)v * g + lane];
    #pragma unroll
    for (int i = 0; i < 8; i++) acc[i] = selfw * bf2f(hv[i]);

    int e = start;
    for (; e + 1 < end; e += 2) {
        int s0 = csr_src[e], s1 = csr_src[e + 1];
        float w0 = csr_w[e], w1 = csr_w[e + 1];
        short8 h0 = h[(size_t)s0 * g + lane];
        short8 h1 = h[(size_t)s1 * g + lane];
        #pragma unroll
        for (int i = 0; i < 8; i++) acc[i] += w0 * bf2f(h0[i]) + w1 * bf2f(h1[i]);
    }
    if (e < end) {
        int s0 = csr_src[e];
        float w0 = csr_w[e];
        short8 h0 = h[(size_t)s0 * g + lane];
        #pragma unroll
        for (int i = 0; i < 8; i++) acc[i] += w0 * bf2f(h0[i]);
    }
    short8 o;
    #pragma unroll
    for (int i = 0; i < 8; i++) o[i] = (short)f2bf(acc[i] * inv_cnt);
    out[(size_t)v * g + lane] = o;
}

// ---------------- weight transpose+convert: Wt[n][k] = bf16(W[k][n]) --------

__global__ void k_wt(const float* __restrict__ W, ushort* __restrict__ Wt, int K, int N) {
    int i = blockIdx.x * blockDim.x + threadIdx.x;
    if (i >= N * K) return;
    int nn = i / K, kk = i % K;
    Wt[i] = f2bf(W[(size_t)kk * N + nn]);
}

// ---------------- MFMA GEMM: C_bf16[M,N] = relu(A[M,K] @ Wt[N,K]^T + bias) --
// bf16 in/out, fp32 accumulate. 128x128 tile, 4 waves, 4x4 16x16x32 MFMAs each.

#define GBM 128
#define GBN 128
#define GBK 32
#define LDSS 40   // LDS row stride in elements (80B, 16B-aligned)

__global__ __launch_bounds__(256) void gemm_mfma(const ushort* __restrict__ A,
                                                 const ushort* __restrict__ Wt,
                                                 const float* __restrict__ bias,
                                                 ushort* __restrict__ C,
                                                 int M, int K, int N, int do_relu) {
    __shared__ ushort As[GBM * LDSS];
    __shared__ ushort Bs[GBN * LDSS];
    int tid = threadIdx.x;
    int wave = tid >> 6;
    int lane = tid & 63;
    int wr = wave >> 1, wc = wave & 1;
    int q = lane >> 4;          // quad 0..3
    int mr = lane & 15;
    int row0 = blockIdx.y * GBM;
    int col0 = blockIdx.x * GBN;

    f32x4 acc[4][4];
    #pragma unroll
    for (int i = 0; i < 4; i++)
        #pragma unroll
        for (int j = 0; j < 4; j++) acc[i][j] = (f32x4){0.f, 0.f, 0.f, 0.f};

    const short8 zero8 = {0, 0, 0, 0, 0, 0, 0, 0};

    for (int k0 = 0; k0 < K; k0 += GBK) {
        #pragma unroll
        for (int it = 0; it < 2; it++) {
            int t = tid + it * 256;
            int r = t >> 2;               // row in tile (0..127)
            int koff = (t & 3) * 8;       // k offset in tile
            int gk = k0 + koff;
            short8 va = zero8;
            int gr = row0 + r;
            if (gr < M && gk < K)
                va = *(const short8*)(A + (size_t)gr * K + gk);
            *(short8*)(As + r * LDSS + koff) = va;
            short8 vb = zero8;
            int gn = col0 + r;
            if (gn < N && gk < K)
                vb = *(const short8*)(Wt + (size_t)gn * K + gk);
            *(short8*)(Bs + r * LDSS + koff) = vb;
        }
        __syncthreads();
        short8 afr[4], bfr[4];
        #pragma unroll
        for (int i = 0; i < 4; i++)
            afr[i] = *(const short8*)(As + (wr * 64 + i * 16 + mr) * LDSS + q * 8);
        #pragma unroll
        for (int j = 0; j < 4; j++)
            bfr[j] = *(const short8*)(Bs + (wc * 64 + j * 16 + mr) * LDSS + q * 8);
        #pragma unroll
        for (int i = 0; i < 4; i++)
            #pragma unroll
            for (int j = 0; j < 4; j++)
                acc[i][j] = __builtin_amdgcn_mfma_f32_16x16x32_bf16(afr[i], bfr[j],
                                                                    acc[i][j], 0, 0, 0);
        __syncthreads();
    }

    // epilogue: C/D layout col=lane&15, row=q*4+reg; emit bf16
    #pragma unroll
    for (int j = 0; j < 4; j++) {
        int col = col0 + wc * 64 + j * 16 + mr;
        if (col >= N) continue;
        float bj = bias[col];
        #pragma unroll
        for (int i = 0; i < 4; i++) {
            int rbase = row0 + wr * 64 + i * 16 + q * 4;
            #pragma unroll
            for (int r = 0; r < 4; r++) {
                int grow = rbase + r;
                if (grow < M) {
                    float v = acc[i][j][r] + bj;
                    if (do_relu) v = fmaxf(v, 0.0f);
                    C[(size_t)grow * N + col] = f2bf(v);
                }
            }
        }
    }
}

// ---------------- final layer ----------------
// one wave per node; K=512 bf16 = 64 lanes x short8 in a single shot

__global__ void k_dot512_bf16(const short8* __restrict__ A, const float4* __restrict__ w,
                              float* __restrict__ out, int n) {
    int wv = (blockIdx.x * blockDim.x + threadIdx.x) >> 6;
    int lane = threadIdx.x & 63;
    if (wv >= n) return;
    short8 a = A[(size_t)wv * 64 + lane];
    float4 w0 = w[lane * 2], w1 = w[lane * 2 + 1];
    float acc = bf2f(a[0]) * w0.x + bf2f(a[1]) * w0.y + bf2f(a[2]) * w0.z + bf2f(a[3]) * w0.w
              + bf2f(a[4]) * w1.x + bf2f(a[5]) * w1.y + bf2f(a[6]) * w1.z + bf2f(a[7]) * w1.w;
    #pragma unroll
    for (int off = 32; off > 0; off >>= 1) acc += __shfl_down(acc, off, 64);
    if (lane == 0) out[wv] = acc;
}

__global__ void k_agg_final(const float* __restrict__ h, float* __restrict__ out,
                            const int* __restrict__ rowptr, const int* __restrict__ csr_src,
                            const float* __restrict__ csr_w, const float* __restrict__ dinv,
                            const float* __restrict__ b5, int n) {
    int v = blockIdx.x * blockDim.x + threadIdx.x;
    if (v >= n) return;
    float acc = dinv[v] * dinv[v] * h[v];
    int end = rowptr[v + 1];
    for (int e = rowptr[v]; e < end; e++) acc += csr_w[e] * h[csr_src[e]];
    float r = acc + b5[0];                 // 'add' aggregation (output layer)
    out[v] = 1.0f / (1.0f + expf(-r));     // sigmoid
}

// ---------------- launch ----------------

extern "C" void kernel_launch(void* const* d_in, const int* in_sizes, int n_in,
                              void* d_out, int out_size, void* d_ws, size_t ws_size,
                              hipStream_t stream) {
    const float* x   = (const float*)d_in[0];
    const int*   ei  = (const int*)d_in[1];
    const float* W[5] = {(const float*)d_in[2], (const float*)d_in[4], (const float*)d_in[6],
                         (const float*)d_in[8], (const float*)d_in[10]};
    const float* b[5] = {(const float*)d_in[3], (const float*)d_in[5], (const float*)d_in[7],
                         (const float*)d_in[9], (const float*)d_in[11]};
    const int n = in_sizes[0] / 16;
    const int E = in_sizes[1] / 2;
    const int dims[6] = {16, 64, 128, 256, 512, 1};

    const int* e_row = ei;          // src
    const int* e_col = ei + E;      // dst

    // workspace layout (same footprint as r2)
    float* bufA_f = (float*)d_ws;                     // n*512 floats region
    float* bufB_f = bufA_f + (size_t)n * 512;         // n*512 floats region
    ushort* bufA  = (ushort*)bufA_f;                  // h (GEMM out, bf16)
    ushort* bufB  = (ushort*)bufB_f;                  // agg out (bf16)
    int*   cnt    = (int*)(bufB_f + (size_t)n * 512); // n
    int*   rowptr = cnt + n;                          // n+1 (pad to n+4)
    int*   cursor = rowptr + n + 4;                   // n
    float* deg    = (float*)(cursor + n);             // n
    float* dinv   = deg + n;                          // n
    int*   csr_src= (int*)(dinv + n);                 // E
    float* csr_w  = (float*)(csr_src + E);            // E
    ushort* wt0   = (ushort*)(csr_w + E);             // bf16 transposed weights
    ushort* wt1   = wt0 + 16 * 64;
    ushort* wt2   = wt1 + 64 * 128;
    ushort* wt3   = wt2 + 128 * 256;
    ushort* wts[4] = {wt0, wt1, wt2, wt3};

    // ---- graph prep ----
    k_zero_int<<<(n + 255) / 256, 256, 0, stream>>>(cnt, n);
    k_count<<<(E + 255) / 256, 256, 0, stream>>>(e_col, cnt, E);
    k_deg_dinv<<<(n + 255) / 256, 256, 0, stream>>>(cnt, deg, dinv, n);
    k_scan<<<1, 1024, 0, stream>>>(cnt, rowptr, cursor, n);
    k_fill<<<(E + 255) / 256, 256, 0, stream>>>(e_row, e_col, dinv, cursor, csr_src, csr_w, E);

    // ---- weight transpose/convert ----
    for (int l = 0; l < 4; l++) {
        int K = dims[l], Nd = dims[l + 1];
        k_wt<<<(K * Nd + 255) / 256, 256, 0, stream>>>(W[l], wts[l], K, Nd);
    }

    // ---- layer 1: fp32 agg -> bf16, then MFMA GEMM -> bf16 h ----
    {
        int K = 16, M = n, Nd = 64;
        int gpb = 256 >> 2;   // 64 nodes / block
        k_agg_pre_f32<<<(n + gpb - 1) / gpb, 256, 0, stream>>>(
            (const float4*)x, (ushort4*)bufB, rowptr, csr_src, csr_w, deg, dinv, n);
        dim3 ggrid((Nd + GBN - 1) / GBN, (M + GBM - 1) / GBM);
        gemm_mfma<<<ggrid, 256, 0, stream>>>(bufB, wts[0], b[0], bufA, M, K, Nd, 1);
    }

    // ---- layers 2..4: bf16 agg -> MFMA GEMM -> bf16 h ----
    for (int l = 1; l < 4; l++) {
        int K = dims[l], M = n, Nd = dims[l + 1];
        int g_shift = (K == 64) ? 3 : (K == 128) ? 4 : 5;   // lanes/node = K/8
        int gpb = 256 >> g_shift;
        k_agg_pre_bf16<<<(n + gpb - 1) / gpb, 256, 0, stream>>>(
            (const short8*)bufA, (short8*)bufB, rowptr, csr_src, csr_w, deg, dinv, n, g_shift);
        dim3 ggrid((Nd + GBN - 1) / GBN, (M + GBM - 1) / GBM);
        gemm_mfma<<<ggrid, 256, 0, stream>>>(bufB, wts[l], b[l], bufA, M, K, Nd, 1);
    }

    // ---- layer 5: bf16 dot + add-aggregate + sigmoid ----
    k_dot512_bf16<<<(n * 64 + 255) / 256, 256, 0, stream>>>(
        (const short8*)bufA, (const float4*)W[4], bufB_f, n);
    k_agg_final<<<(n + 255) / 256, 256, 0, stream>>>(bufB_f, (float*)d_out, rowptr,
                                                     csr_src, csr_w, dinv, b[4], n);
}

// Round 5
// 306.670 us; speedup vs baseline: 2.1084x; 1.0066x over previous
//
#include <hip/hip_runtime.h>
#include <hip/hip_bf16.h>
#include <math.h>

// GCN 5-layer: dims 16->64->128->256->512->1, N=20000, E=320000.
// Round 4: aggregation MLP fix — unroll-4 with hoisted edge indices so 4
// independent 16B h-row gathers are in flight per lane (was a dependent
// 2-deep chain, VALUBusy 9.5%). Fused deg/dinv into scan; single k_wt_all
// kernel for all 4 weight transposes (fewer launches).

#define N_NODES 20000
#define N_EDGES 320000

typedef __attribute__((ext_vector_type(8))) short short8;
typedef __attribute__((ext_vector_type(4))) float f32x4;

__device__ inline ushort f2bf(float f) {
    __hip_bfloat16 h = __float2bfloat16(f);   // RNE
    return *(ushort*)&h;
}

__device__ inline float bf2f(short s) {
    union { unsigned int u; float f; } c;
    c.u = ((unsigned int)(unsigned short)s) << 16;
    return c.f;
}

// ---------------- graph prep ----------------

__global__ void k_zero_int(int* p, int n) {
    int i = blockIdx.x * blockDim.x + threadIdx.x;
    if (i < n) p[i] = 0;
}

__global__ void k_count(const int* __restrict__ col, int* __restrict__ cnt, int E) {
    int e = blockIdx.x * blockDim.x + threadIdx.x;
    if (e < E) atomicAdd(&cnt[col[e]], 1);
}

// single-block scan: cnt[n] -> rowptr[n+1] + cursor; also deg/dinv (fused)
__global__ void k_scan(const int* __restrict__ cnt, int* __restrict__ rowptr,
                       int* __restrict__ cursor, float* __restrict__ deg,
                       float* __restrict__ dinv, int n) {
    __shared__ int ssum[1024];
    int tid = threadIdx.x;                 // blockDim = 1024
    const int CH = (n + 1023) / 1024;
    int begin = tid * CH;
    int local = 0;
    for (int i = 0; i < CH; i++) {
        int idx = begin + i;
        if (idx < n) local += cnt[idx];
    }
    ssum[tid] = local;
    __syncthreads();
    for (int off = 1; off < 1024; off <<= 1) {
        int v = ssum[tid];
        int add = (tid >= off) ? ssum[tid - off] : 0;
        __syncthreads();
        ssum[tid] = v + add;
        __syncthreads();
    }
    int run = (tid == 0) ? 0 : ssum[tid - 1];
    for (int i = 0; i < CH; i++) {
        int idx = begin + i;
        if (idx < n) {
            int c = cnt[idx];
            rowptr[idx] = run;
            cursor[idx] = run;
            run += c;
            float d = (float)(c + 1);      // in-degree + self-loop
            deg[idx] = d;
            dinv[idx] = rsqrtf(d);
        }
    }
    if (tid == 1023) rowptr[n] = ssum[1023];
}

__global__ void k_fill(const int* __restrict__ row, const int* __restrict__ col,
                       const float* __restrict__ dinv, int* __restrict__ cursor,
                       int* __restrict__ csr_src, float* __restrict__ csr_w, int E) {
    int e = blockIdx.x * blockDim.x + threadIdx.x;
    if (e >= E) return;
    int s = row[e], d = col[e];
    int pos = atomicAdd(&cursor[d], 1);
    csr_src[pos] = s;
    csr_w[pos] = dinv[s] * dinv[d];
}

// ---------------- layer-1 pre-aggregation (fp32 x -> bf16 out), d=16 --------

__global__ void k_agg_pre_f32(const float4* __restrict__ h, ushort4* __restrict__ out,
                              const int* __restrict__ rowptr, const int* __restrict__ csr_src,
                              const float* __restrict__ csr_w, const float* __restrict__ deg,
                              const float* __restrict__ dinv, int n) {
    const int g_shift = 2;                       // d=16 -> 4 float4 lanes per node
    int g = 1 << g_shift;
    int grp = threadIdx.x >> g_shift;
    int lane = threadIdx.x & (g - 1);
    int gpb = blockDim.x >> g_shift;
    int v = blockIdx.x * gpb + grp;
    if (v >= n) return;
    float dv = dinv[v];
    float selfw = dv * dv;
    float inv_cnt = 1.0f / deg[v];
    int start = rowptr[v], end = rowptr[v + 1];
    float4 hv = h[(size_t)v * g + lane];
    float4 acc = make_float4(selfw * hv.x, selfw * hv.y, selfw * hv.z, selfw * hv.w);
    int e = start;
    for (; e + 4 <= end; e += 4) {
        int s0 = csr_src[e], s1 = csr_src[e + 1], s2 = csr_src[e + 2], s3 = csr_src[e + 3];
        float4 h0 = h[(size_t)s0 * g + lane];
        float4 h1 = h[(size_t)s1 * g + lane];
        float4 h2 = h[(size_t)s2 * g + lane];
        float4 h3 = h[(size_t)s3 * g + lane];
        float w0 = csr_w[e], w1 = csr_w[e + 1], w2 = csr_w[e + 2], w3 = csr_w[e + 3];
        acc.x += w0 * h0.x + w1 * h1.x + w2 * h2.x + w3 * h3.x;
        acc.y += w0 * h0.y + w1 * h1.y + w2 * h2.y + w3 * h3.y;
        acc.z += w0 * h0.z + w1 * h1.z + w2 * h2.z + w3 * h3.z;
        acc.w += w0 * h0.w + w1 * h1.w + w2 * h2.w + w3 * h3.w;
    }
    for (; e < end; e++) {
        int s = csr_src[e];
        float w = csr_w[e];
        float4 hs = h[(size_t)s * g + lane];
        acc.x += w * hs.x; acc.y += w * hs.y; acc.z += w * hs.z; acc.w += w * hs.w;
    }
    ushort4 o;
    o.x = f2bf(acc.x * inv_cnt);
    o.y = f2bf(acc.y * inv_cnt);
    o.z = f2bf(acc.z * inv_cnt);
    o.w = f2bf(acc.w * inv_cnt);
    out[(size_t)v * g + lane] = o;
}

// ---------------- bf16 pre-aggregation (layers 2..4), unroll-4 MLP ----------

__global__ void k_agg_pre_bf16(const short8* __restrict__ h, short8* __restrict__ out,
                               const int* __restrict__ rowptr, const int* __restrict__ csr_src,
                               const float* __restrict__ csr_w, const float* __restrict__ deg,
                               const float* __restrict__ dinv, int n, int g_shift) {
    int g = 1 << g_shift;                        // lanes per node = d/8
    int grp = threadIdx.x >> g_shift;
    int lane = threadIdx.x & (g - 1);
    int gpb = blockDim.x >> g_shift;
    int v = blockIdx.x * gpb + grp;
    if (v >= n) return;
    float dv = dinv[v];
    float selfw = dv * dv;
    float inv_cnt = 1.0f / deg[v];
    int start = rowptr[v], end = rowptr[v + 1];

    float acc[8];
    short8 hv = h[(size_t)v * g + lane];
    #pragma unroll
    for (int i = 0; i < 8; i++) acc[i] = selfw * bf2f(hv[i]);

    int e = start;
    for (; e + 4 <= end; e += 4) {
        int s0 = csr_src[e], s1 = csr_src[e + 1], s2 = csr_src[e + 2], s3 = csr_src[e + 3];
        short8 h0 = h[(size_t)s0 * g + lane];
        short8 h1 = h[(size_t)s1 * g + lane];
        short8 h2 = h[(size_t)s2 * g + lane];
        short8 h3 = h[(size_t)s3 * g + lane];
        float w0 = csr_w[e], w1 = csr_w[e + 1], w2 = csr_w[e + 2], w3 = csr_w[e + 3];
        #pragma unroll
        for (int i = 0; i < 8; i++)
            acc[i] += w0 * bf2f(h0[i]) + w1 * bf2f(h1[i])
                    + w2 * bf2f(h2[i]) + w3 * bf2f(h3[i]);
    }
    for (; e < end; e++) {
        int s0 = csr_src[e];
        float w0 = csr_w[e];
        short8 h0 = h[(size_t)s0 * g + lane];
        #pragma unroll
        for (int i = 0; i < 8; i++) acc[i] += w0 * bf2f(h0[i]);
    }
    short8 o;
    #pragma unroll
    for (int i = 0; i < 8; i++) o[i] = (short)f2bf(acc[i] * inv_cnt);
    out[(size_t)v * g + lane] = o;
}

// ---------------- fused weight transpose+convert for all 4 layers -----------
// segments (N*K): 1024, 8192, 32768, 131072 -> total 173056

__global__ void k_wt_all(const float* __restrict__ W0, const float* __restrict__ W1,
                         const float* __restrict__ W2, const float* __restrict__ W3,
                         ushort* __restrict__ T0, ushort* __restrict__ T1,
                         ushort* __restrict__ T2, ushort* __restrict__ T3) {
    int i = blockIdx.x * blockDim.x + threadIdx.x;
    const float* W; ushort* T; int K, N, j;
    if (i < 1024)        { W = W0; T = T0; K = 16;  N = 64;  j = i; }
    else if (i < 9216)   { W = W1; T = T1; K = 64;  N = 128; j = i - 1024; }
    else if (i < 41984)  { W = W2; T = T2; K = 128; N = 256; j = i - 9216; }
    else if (i < 173056) { W = W3; T = T3; K = 256; N = 512; j = i - 41984; }
    else return;
    int nn = j / K, kk = j - nn * K;
    T[(size_t)nn * K + kk] = f2bf(W[(size_t)kk * N + nn]);
}

// ---------------- MFMA GEMM: C_bf16[M,N] = relu(A[M,K] @ Wt[N,K]^T + bias) --

#define GBM 128
#define GBN 128
#define GBK 32
#define LDSS 40   // LDS row stride in elements (80B, 16B-aligned)

__global__ __launch_bounds__(256) void gemm_mfma(const ushort* __restrict__ A,
                                                 const ushort* __restrict__ Wt,
                                                 const float* __restrict__ bias,
                                                 ushort* __restrict__ C,
                                                 int M, int K, int N, int do_relu) {
    __shared__ ushort As[GBM * LDSS];
    __shared__ ushort Bs[GBN * LDSS];
    int tid = threadIdx.x;
    int wave = tid >> 6;
    int lane = tid & 63;
    int wr = wave >> 1, wc = wave & 1;
    int q = lane >> 4;          // quad 0..3
    int mr = lane & 15;
    int row0 = blockIdx.y * GBM;
    int col0 = blockIdx.x * GBN;

    f32x4 acc[4][4];
    #pragma unroll
    for (int i = 0; i < 4; i++)
        #pragma unroll
        for (int j = 0; j < 4; j++) acc[i][j] = (f32x4){0.f, 0.f, 0.f, 0.f};

    const short8 zero8 = {0, 0, 0, 0, 0, 0, 0, 0};

    for (int k0 = 0; k0 < K; k0 += GBK) {
        #pragma unroll
        for (int it = 0; it < 2; it++) {
            int t = tid + it * 256;
            int r = t >> 2;               // row in tile (0..127)
            int koff = (t & 3) * 8;       // k offset in tile
            int gk = k0 + koff;
            short8 va = zero8;
            int gr = row0 + r;
            if (gr < M && gk < K)
                va = *(const short8*)(A + (size_t)gr * K + gk);
            *(short8*)(As + r * LDSS + koff) = va;
            short8 vb = zero8;
            int gn = col0 + r;
            if (gn < N && gk < K)
                vb = *(const short8*)(Wt + (size_t)gn * K + gk);
            *(short8*)(Bs + r * LDSS + koff) = vb;
        }
        __syncthreads();
        short8 afr[4], bfr[4];
        #pragma unroll
        for (int i = 0; i < 4; i++)
            afr[i] = *(const short8*)(As + (wr * 64 + i * 16 + mr) * LDSS + q * 8);
        #pragma unroll
        for (int j = 0; j < 4; j++)
            bfr[j] = *(const short8*)(Bs + (wc * 64 + j * 16 + mr) * LDSS + q * 8);
        #pragma unroll
        for (int i = 0; i < 4; i++)
            #pragma unroll
            for (int j = 0; j < 4; j++)
                acc[i][j] = __builtin_amdgcn_mfma_f32_16x16x32_bf16(afr[i], bfr[j],
                                                                    acc[i][j], 0, 0, 0);
        __syncthreads();
    }

    // epilogue: C/D layout col=lane&15, row=q*4+reg; emit bf16
    #pragma unroll
    for (int j = 0; j < 4; j++) {
        int col = col0 + wc * 64 + j * 16 + mr;
        if (col >= N) continue;
        float bj = bias[col];
        #pragma unroll
        for (int i = 0; i < 4; i++) {
            int rbase = row0 + wr * 64 + i * 16 + q * 4;
            #pragma unroll
            for (int r = 0; r < 4; r++) {
                int grow = rbase + r;
                if (grow < M) {
                    float v = acc[i][j][r] + bj;
                    if (do_relu) v = fmaxf(v, 0.0f);
                    C[(size_t)grow * N + col] = f2bf(v);
                }
            }
        }
    }
}

// ---------------- final layer ----------------

__global__ void k_dot512_bf16(const short8* __restrict__ A, const float4* __restrict__ w,
                              float* __restrict__ out, int n) {
    int wv = (blockIdx.x * blockDim.x + threadIdx.x) >> 6;
    int lane = threadIdx.x & 63;
    if (wv >= n) return;
    short8 a = A[(size_t)wv * 64 + lane];
    float4 w0 = w[lane * 2], w1 = w[lane * 2 + 1];
    float acc = bf2f(a[0]) * w0.x + bf2f(a[1]) * w0.y + bf2f(a[2]) * w0.z + bf2f(a[3]) * w0.w
              + bf2f(a[4]) * w1.x + bf2f(a[5]) * w1.y + bf2f(a[6]) * w1.z + bf2f(a[7]) * w1.w;
    #pragma unroll
    for (int off = 32; off > 0; off >>= 1) acc += __shfl_down(acc, off, 64);
    if (lane == 0) out[wv] = acc;
}

__global__ void k_agg_final(const float* __restrict__ h, float* __restrict__ out,
                            const int* __restrict__ rowptr, const int* __restrict__ csr_src,
                            const float* __restrict__ csr_w, const float* __restrict__ dinv,
                            const float* __restrict__ b5, int n) {
    int v = blockIdx.x * blockDim.x + threadIdx.x;
    if (v >= n) return;
    float acc = dinv[v] * dinv[v] * h[v];
    int end = rowptr[v + 1];
    for (int e = rowptr[v]; e < end; e++) acc += csr_w[e] * h[csr_src[e]];
    float r = acc + b5[0];                 // 'add' aggregation (output layer)
    out[v] = 1.0f / (1.0f + expf(-r));     // sigmoid
}

// ---------------- launch ----------------

extern "C" void kernel_launch(void* const* d_in, const int* in_sizes, int n_in,
                              void* d_out, int out_size, void* d_ws, size_t ws_size,
                              hipStream_t stream) {
    const float* x   = (const float*)d_in[0];
    const int*   ei  = (const int*)d_in[1];
    const float* W[5] = {(const float*)d_in[2], (const float*)d_in[4], (const float*)d_in[6],
                         (const float*)d_in[8], (const float*)d_in[10]};
    const float* b[5] = {(const float*)d_in[3], (const float*)d_in[5], (const float*)d_in[7],
                         (const float*)d_in[9], (const float*)d_in[11]};
    const int n = in_sizes[0] / 16;
    const int E = in_sizes[1] / 2;
    const int dims[6] = {16, 64, 128, 256, 512, 1};

    const int* e_row = ei;          // src
    const int* e_col = ei + E;      // dst

    // workspace layout
    float* bufA_f = (float*)d_ws;                     // n*512 floats region
    float* bufB_f = bufA_f + (size_t)n * 512;         // n*512 floats region
    ushort* bufA  = (ushort*)bufA_f;                  // h (GEMM out, bf16)
    ushort* bufB  = (ushort*)bufB_f;                  // agg out (bf16)
    int*   cnt    = (int*)(bufB_f + (size_t)n * 512); // n
    int*   rowptr = cnt + n;                          // n+1 (pad to n+4)
    int*   cursor = rowptr + n + 4;                   // n
    float* deg    = (float*)(cursor + n);             // n
    float* dinv   = deg + n;                          // n
    int*   csr_src= (int*)(dinv + n);                 // E
    float* csr_w  = (float*)(csr_src + E);            // E
    ushort* wt0   = (ushort*)(csr_w + E);             // bf16 transposed weights
    ushort* wt1   = wt0 + 16 * 64;
    ushort* wt2   = wt1 + 64 * 128;
    ushort* wt3   = wt2 + 128 * 256;
    ushort* wts[4] = {wt0, wt1, wt2, wt3};

    // ---- graph prep ----
    k_zero_int<<<(n + 255) / 256, 256, 0, stream>>>(cnt, n);
    k_count<<<(E + 255) / 256, 256, 0, stream>>>(e_col, cnt, E);
    k_scan<<<1, 1024, 0, stream>>>(cnt, rowptr, cursor, deg, dinv, n);
    k_fill<<<(E + 255) / 256, 256, 0, stream>>>(e_row, e_col, dinv, cursor, csr_src, csr_w, E);

    // ---- weight transpose/convert (one kernel, all 4 layers) ----
    k_wt_all<<<(173056 + 255) / 256, 256, 0, stream>>>(W[0], W[1], W[2], W[3],
                                                       wt0, wt1, wt2, wt3);

    // ---- layer 1: fp32 agg -> bf16, then MFMA GEMM -> bf16 h ----
    {
        int K = 16, M = n, Nd = 64;
        int gpb = 256 >> 2;   // 64 nodes / block
        k_agg_pre_f32<<<(n + gpb - 1) / gpb, 256, 0, stream>>>(
            (const float4*)x, (ushort4*)bufB, rowptr, csr_src, csr_w, deg, dinv, n);
        dim3 ggrid((Nd + GBN - 1) / GBN, (M + GBM - 1) / GBM);
        gemm_mfma<<<ggrid, 256, 0, stream>>>(bufB, wts[0], b[0], bufA, M, K, Nd, 1);
    }

    // ---- layers 2..4: bf16 agg -> MFMA GEMM -> bf16 h ----
    for (int l = 1; l < 4; l++) {
        int K = dims[l], M = n, Nd = dims[l + 1];
        int g_shift = (K == 64) ? 3 : (K == 128) ? 4 : 5;   // lanes/node = K/8
        int gpb = 256 >> g_shift;
        k_agg_pre_bf16<<<(n + gpb - 1) / gpb, 256, 0, stream>>>(
            (const short8*)bufA, (short8*)bufB, rowptr, csr_src, csr_w, deg, dinv, n, g_shift);
        dim3 ggrid((Nd + GBN - 1) / GBN, (M + GBM - 1) / GBM);
        gemm_mfma<<<ggrid, 256, 0, stream>>>(bufB, wts[l], b[l], bufA, M, K, Nd, 1);
    }

    // ---- layer 5: bf16 dot + add-aggregate + sigmoid ----
    k_dot512_bf16<<<(n * 64 + 255) / 256, 256, 0, stream>>>(
        (const short8*)bufA, (const float4*)W[4], bufB_f, n);
    k_agg_final<<<(n + 255) / 256, 256, 0, stream>>>(bufB_f, (float*)d_out, rowptr,
                                                     csr_src, csr_w, dinv, b[4], n);
}

// Round 6
// 256.007 us; speedup vs baseline: 2.5256x; 1.1979x over previous
//
#include <hip/hip_runtime.h>
#include <hip/hip_bf16.h>
#include <math.h>

// GCN 5-layer: dims 16->64->128->256->512->1, N=20000, E=320000.
// Round 5: the single-block k_scan (57us, one CU busy) is replaced by a
// 3-phase parallel scan (block-local scan -> wave scan of block sums ->
// offset add + deg/dinv), all coalesced. Everything else unchanged.

#define N_NODES 20000
#define N_EDGES 320000

typedef __attribute__((ext_vector_type(8))) short short8;
typedef __attribute__((ext_vector_type(4))) float f32x4;

__device__ inline ushort f2bf(float f) {
    __hip_bfloat16 h = __float2bfloat16(f);   // RNE
    return *(ushort*)&h;
}

__device__ inline float bf2f(short s) {
    union { unsigned int u; float f; } c;
    c.u = ((unsigned int)(unsigned short)s) << 16;
    return c.f;
}

// ---------------- graph prep ----------------

__global__ void k_zero_int(int* p, int n) {
    int i = blockIdx.x * blockDim.x + threadIdx.x;
    if (i < n) p[i] = 0;
}

__global__ void k_count(const int* __restrict__ col, int* __restrict__ cnt, int E) {
    int e = blockIdx.x * blockDim.x + threadIdx.x;
    if (e < E) atomicAdd(&cnt[col[e]], 1);
}

// ---- 3-phase scan: cnt[n] -> rowptr[n+1], cursor, deg, dinv ----
// Phase A: 1024 elems/block, block-local exclusive prefix + block total.
__global__ __launch_bounds__(256) void k_scan_a(const int* __restrict__ cnt,
                                                int* __restrict__ rowptr,
                                                int* __restrict__ bsum, int n) {
    __shared__ int s[256];
    int b = blockIdx.x, tid = threadIdx.x;
    int base = b * 1024 + tid * 4;
    int v0 = 0, v1 = 0, v2 = 0, v3 = 0;
    if (base + 3 < n) {
        int4 c = *(const int4*)(cnt + base);
        v0 = c.x; v1 = c.y; v2 = c.z; v3 = c.w;
    } else {
        if (base < n)     v0 = cnt[base];
        if (base + 1 < n) v1 = cnt[base + 1];
        if (base + 2 < n) v2 = cnt[base + 2];
        if (base + 3 < n) v3 = cnt[base + 3];
    }
    s[tid] = v0 + v1 + v2 + v3;
    __syncthreads();
    for (int off = 1; off < 256; off <<= 1) {
        int x = s[tid];
        int add = (tid >= off) ? s[tid - off] : 0;
        __syncthreads();
        s[tid] = x + add;
        __syncthreads();
    }
    int excl = (tid == 0) ? 0 : s[tid - 1];
    if (base < n)     rowptr[base]     = excl;
    if (base + 1 < n) rowptr[base + 1] = excl + v0;
    if (base + 2 < n) rowptr[base + 2] = excl + v0 + v1;
    if (base + 3 < n) rowptr[base + 3] = excl + v0 + v1 + v2;
    if (tid == 255) bsum[b] = s[255];
}

// Phase B: single wave scans block sums (nblk <= 64) -> exclusive offsets;
// writes rowptr[n] = grand total.
__global__ void k_scan_b(int* __restrict__ bsum, int* __restrict__ rowptr,
                         int n, int nblk) {
    int tid = threadIdx.x;   // blockDim = 64
    int orig = (tid < nblk) ? bsum[tid] : 0;
    int v = orig;
    #pragma unroll
    for (int off = 1; off < 64; off <<= 1) {
        int u = __shfl_up(v, off, 64);
        if (tid >= off) v += u;
    }
    if (tid < nblk) bsum[tid] = v - orig;          // exclusive offset
    if (tid == nblk - 1) rowptr[n] = v;            // grand total
}

// Phase C: add block offsets; emit cursor, deg, dinv (all coalesced).
__global__ void k_scan_c(const int* __restrict__ cnt, int* __restrict__ rowptr,
                         int* __restrict__ cursor, float* __restrict__ deg,
                         float* __restrict__ dinv, const int* __restrict__ bsum, int n) {
    int i = blockIdx.x * blockDim.x + threadIdx.x;
    if (i >= n) return;
    int r = rowptr[i] + bsum[i >> 10];
    rowptr[i] = r;
    cursor[i] = r;
    int c = cnt[i];
    float d = (float)(c + 1);      // in-degree + self-loop
    deg[i] = d;
    dinv[i] = rsqrtf(d);
}

__global__ void k_fill(const int* __restrict__ row, const int* __restrict__ col,
                       const float* __restrict__ dinv, int* __restrict__ cursor,
                       int* __restrict__ csr_src, float* __restrict__ csr_w, int E) {
    int e = blockIdx.x * blockDim.x + threadIdx.x;
    if (e >= E) return;
    int s = row[e], d = col[e];
    int pos = atomicAdd(&cursor[d], 1);
    csr_src[pos] = s;
    csr_w[pos] = dinv[s] * dinv[d];
}

// ---------------- layer-1 pre-aggregation (fp32 x -> bf16 out), d=16 --------

__global__ void k_agg_pre_f32(const float4* __restrict__ h, ushort4* __restrict__ out,
                              const int* __restrict__ rowptr, const int* __restrict__ csr_src,
                              const float* __restrict__ csr_w, const float* __restrict__ deg,
                              const float* __restrict__ dinv, int n) {
    const int g_shift = 2;                       // d=16 -> 4 float4 lanes per node
    int g = 1 << g_shift;
    int grp = threadIdx.x >> g_shift;
    int lane = threadIdx.x & (g - 1);
    int gpb = blockDim.x >> g_shift;
    int v = blockIdx.x * gpb + grp;
    if (v >= n) return;
    float dv = dinv[v];
    float selfw = dv * dv;
    float inv_cnt = 1.0f / deg[v];
    int start = rowptr[v], end = rowptr[v + 1];
    float4 hv = h[(size_t)v * g + lane];
    float4 acc = make_float4(selfw * hv.x, selfw * hv.y, selfw * hv.z, selfw * hv.w);
    int e = start;
    for (; e + 4 <= end; e += 4) {
        int s0 = csr_src[e], s1 = csr_src[e + 1], s2 = csr_src[e + 2], s3 = csr_src[e + 3];
        float4 h0 = h[(size_t)s0 * g + lane];
        float4 h1 = h[(size_t)s1 * g + lane];
        float4 h2 = h[(size_t)s2 * g + lane];
        float4 h3 = h[(size_t)s3 * g + lane];
        float w0 = csr_w[e], w1 = csr_w[e + 1], w2 = csr_w[e + 2], w3 = csr_w[e + 3];
        acc.x += w0 * h0.x + w1 * h1.x + w2 * h2.x + w3 * h3.x;
        acc.y += w0 * h0.y + w1 * h1.y + w2 * h2.y + w3 * h3.y;
        acc.z += w0 * h0.z + w1 * h1.z + w2 * h2.z + w3 * h3.z;
        acc.w += w0 * h0.w + w1 * h1.w + w2 * h2.w + w3 * h3.w;
    }
    for (; e < end; e++) {
        int s = csr_src[e];
        float w = csr_w[e];
        float4 hs = h[(size_t)s * g + lane];
        acc.x += w * hs.x; acc.y += w * hs.y; acc.z += w * hs.z; acc.w += w * hs.w;
    }
    ushort4 o;
    o.x = f2bf(acc.x * inv_cnt);
    o.y = f2bf(acc.y * inv_cnt);
    o.z = f2bf(acc.z * inv_cnt);
    o.w = f2bf(acc.w * inv_cnt);
    out[(size_t)v * g + lane] = o;
}

// ---------------- bf16 pre-aggregation (layers 2..4), unroll-4 MLP ----------

__global__ void k_agg_pre_bf16(const short8* __restrict__ h, short8* __restrict__ out,
                               const int* __restrict__ rowptr, const int* __restrict__ csr_src,
                               const float* __restrict__ csr_w, const float* __restrict__ deg,
                               const float* __restrict__ dinv, int n, int g_shift) {
    int g = 1 << g_shift;                        // lanes per node = d/8
    int grp = threadIdx.x >> g_shift;
    int lane = threadIdx.x & (g - 1);
    int gpb = blockDim.x >> g_shift;
    int v = blockIdx.x * gpb + grp;
    if (v >= n) return;
    float dv = dinv[v];
    float selfw = dv * dv;
    float inv_cnt = 1.0f / deg[v];
    int start = rowptr[v], end = rowptr[v + 1];

    float acc[8];
    short8 hv = h[(size_t)v * g + lane];
    #pragma unroll
    for (int i = 0; i < 8; i++) acc[i] = selfw * bf2f(hv[i]);

    int e = start;
    for (; e + 4 <= end; e += 4) {
        int s0 = csr_src[e], s1 = csr_src[e + 1], s2 = csr_src[e + 2], s3 = csr_src[e + 3];
        short8 h0 = h[(size_t)s0 * g + lane];
        short8 h1 = h[(size_t)s1 * g + lane];
        short8 h2 = h[(size_t)s2 * g + lane];
        short8 h3 = h[(size_t)s3 * g + lane];
        float w0 = csr_w[e], w1 = csr_w[e + 1], w2 = csr_w[e + 2], w3 = csr_w[e + 3];
        #pragma unroll
        for (int i = 0; i < 8; i++)
            acc[i] += w0 * bf2f(h0[i]) + w1 * bf2f(h1[i])
                    + w2 * bf2f(h2[i]) + w3 * bf2f(h3[i]);
    }
    for (; e < end; e++) {
        int s0 = csr_src[e];
        float w0 = csr_w[e];
        short8 h0 = h[(size_t)s0 * g + lane];
        #pragma unroll
        for (int i = 0; i < 8; i++) acc[i] += w0 * bf2f(h0[i]);
    }
    short8 o;
    #pragma unroll
    for (int i = 0; i < 8; i++) o[i] = (short)f2bf(acc[i] * inv_cnt);
    out[(size_t)v * g + lane] = o;
}

// ---------------- fused weight transpose+convert for all 4 layers -----------

__global__ void k_wt_all(const float* __restrict__ W0, const float* __restrict__ W1,
                         const float* __restrict__ W2, const float* __restrict__ W3,
                         ushort* __restrict__ T0, ushort* __restrict__ T1,
                         ushort* __restrict__ T2, ushort* __restrict__ T3) {
    int i = blockIdx.x * blockDim.x + threadIdx.x;
    const float* W; ushort* T; int K, N, j;
    if (i < 1024)        { W = W0; T = T0; K = 16;  N = 64;  j = i; }
    else if (i < 9216)   { W = W1; T = T1; K = 64;  N = 128; j = i - 1024; }
    else if (i < 41984)  { W = W2; T = T2; K = 128; N = 256; j = i - 9216; }
    else if (i < 173056) { W = W3; T = T3; K = 256; N = 512; j = i - 41984; }
    else return;
    int nn = j / K, kk = j - nn * K;
    T[(size_t)nn * K + kk] = f2bf(W[(size_t)kk * N + nn]);
}

// ---------------- MFMA GEMM: C_bf16[M,N] = relu(A[M,K] @ Wt[N,K]^T + bias) --

#define GBM 128
#define GBN 128
#define GBK 32
#define LDSS 40   // LDS row stride in elements (80B, 16B-aligned)

__global__ __launch_bounds__(256) void gemm_mfma(const ushort* __restrict__ A,
                                                 const ushort* __restrict__ Wt,
                                                 const float* __restrict__ bias,
                                                 ushort* __restrict__ C,
                                                 int M, int K, int N, int do_relu) {
    __shared__ ushort As[GBM * LDSS];
    __shared__ ushort Bs[GBN * LDSS];
    int tid = threadIdx.x;
    int wave = tid >> 6;
    int lane = tid & 63;
    int wr = wave >> 1, wc = wave & 1;
    int q = lane >> 4;          // quad 0..3
    int mr = lane & 15;
    int row0 = blockIdx.y * GBM;
    int col0 = blockIdx.x * GBN;

    f32x4 acc[4][4];
    #pragma unroll
    for (int i = 0; i < 4; i++)
        #pragma unroll
        for (int j = 0; j < 4; j++) acc[i][j] = (f32x4){0.f, 0.f, 0.f, 0.f};

    const short8 zero8 = {0, 0, 0, 0, 0, 0, 0, 0};

    for (int k0 = 0; k0 < K; k0 += GBK) {
        #pragma unroll
        for (int it = 0; it < 2; it++) {
            int t = tid + it * 256;
            int r = t >> 2;               // row in tile (0..127)
            int koff = (t & 3) * 8;       // k offset in tile
            int gk = k0 + koff;
            short8 va = zero8;
            int gr = row0 + r;
            if (gr < M && gk < K)
                va = *(const short8*)(A + (size_t)gr * K + gk);
            *(short8*)(As + r * LDSS + koff) = va;
            short8 vb = zero8;
            int gn = col0 + r;
            if (gn < N && gk < K)
                vb = *(const short8*)(Wt + (size_t)gn * K + gk);
            *(short8*)(Bs + r * LDSS + koff) = vb;
        }
        __syncthreads();
        short8 afr[4], bfr[4];
        #pragma unroll
        for (int i = 0; i < 4; i++)
            afr[i] = *(const short8*)(As + (wr * 64 + i * 16 + mr) * LDSS + q * 8);
        #pragma unroll
        for (int j = 0; j < 4; j++)
            bfr[j] = *(const short8*)(Bs + (wc * 64 + j * 16 + mr) * LDSS + q * 8);
        #pragma unroll
        for (int i = 0; i < 4; i++)
            #pragma unroll
            for (int j = 0; j < 4; j++)
                acc[i][j] = __builtin_amdgcn_mfma_f32_16x16x32_bf16(afr[i], bfr[j],
                                                                    acc[i][j], 0, 0, 0);
        __syncthreads();
    }

    // epilogue: C/D layout col=lane&15, row=q*4+reg; emit bf16
    #pragma unroll
    for (int j = 0; j < 4; j++) {
        int col = col0 + wc * 64 + j * 16 + mr;
        if (col >= N) continue;
        float bj = bias[col];
        #pragma unroll
        for (int i = 0; i < 4; i++) {
            int rbase = row0 + wr * 64 + i * 16 + q * 4;
            #pragma unroll
            for (int r = 0; r < 4; r++) {
                int grow = rbase + r;
                if (grow < M) {
                    float v = acc[i][j][r] + bj;
                    if (do_relu) v = fmaxf(v, 0.0f);
                    C[(size_t)grow * N + col] = f2bf(v);
                }
            }
        }
    }
}

// ---------------- final layer ----------------

__global__ void k_dot512_bf16(const short8* __restrict__ A, const float4* __restrict__ w,
                              float* __restrict__ out, int n) {
    int wv = (blockIdx.x * blockDim.x + threadIdx.x) >> 6;
    int lane = threadIdx.x & 63;
    if (wv >= n) return;
    short8 a = A[(size_t)wv * 64 + lane];
    float4 w0 = w[lane * 2], w1 = w[lane * 2 + 1];
    float acc = bf2f(a[0]) * w0.x + bf2f(a[1]) * w0.y + bf2f(a[2]) * w0.z + bf2f(a[3]) * w0.w
              + bf2f(a[4]) * w1.x + bf2f(a[5]) * w1.y + bf2f(a[6]) * w1.z + bf2f(a[7]) * w1.w;
    #pragma unroll
    for (int off = 32; off > 0; off >>= 1) acc += __shfl_down(acc, off, 64);
    if (lane == 0) out[wv] = acc;
}

__global__ void k_agg_final(const float* __restrict__ h, float* __restrict__ out,
                            const int* __restrict__ rowptr, const int* __restrict__ csr_src,
                            const float* __restrict__ csr_w, const float* __restrict__ dinv,
                            const float* __restrict__ b5, int n) {
    int v = blockIdx.x * blockDim.x + threadIdx.x;
    if (v >= n) return;
    float acc = dinv[v] * dinv[v] * h[v];
    int end = rowptr[v + 1];
    for (int e = rowptr[v]; e < end; e++) acc += csr_w[e] * h[csr_src[e]];
    float r = acc + b5[0];                 // 'add' aggregation (output layer)
    out[v] = 1.0f / (1.0f + expf(-r));     // sigmoid
}

// ---------------- launch ----------------

extern "C" void kernel_launch(void* const* d_in, const int* in_sizes, int n_in,
                              void* d_out, int out_size, void* d_ws, size_t ws_size,
                              hipStream_t stream) {
    const float* x   = (const float*)d_in[0];
    const int*   ei  = (const int*)d_in[1];
    const float* W[5] = {(const float*)d_in[2], (const float*)d_in[4], (const float*)d_in[6],
                         (const float*)d_in[8], (const float*)d_in[10]};
    const float* b[5] = {(const float*)d_in[3], (const float*)d_in[5], (const float*)d_in[7],
                         (const float*)d_in[9], (const float*)d_in[11]};
    const int n = in_sizes[0] / 16;
    const int E = in_sizes[1] / 2;
    const int dims[6] = {16, 64, 128, 256, 512, 1};

    const int* e_row = ei;          // src
    const int* e_col = ei + E;      // dst

    // workspace layout
    float* bufA_f = (float*)d_ws;                     // n*512 floats region
    float* bufB_f = bufA_f + (size_t)n * 512;         // n*512 floats region
    ushort* bufA  = (ushort*)bufA_f;                  // h (GEMM out, bf16)
    ushort* bufB  = (ushort*)bufB_f;                  // agg out (bf16)
    int*   cnt    = (int*)(bufB_f + (size_t)n * 512); // n
    int*   rowptr = cnt + n;                          // n+1 (pad to n+4)
    int*   cursor = rowptr + n + 4;                   // n
    float* deg    = (float*)(cursor + n);             // n
    float* dinv   = deg + n;                          // n
    int*   csr_src= (int*)(dinv + n);                 // E
    float* csr_w  = (float*)(csr_src + E);            // E
    ushort* wt0   = (ushort*)(csr_w + E);             // bf16 transposed weights
    ushort* wt1   = wt0 + 16 * 64;
    ushort* wt2   = wt1 + 64 * 128;
    ushort* wt3   = wt2 + 128 * 256;
    int*   bsum   = (int*)(wt3 + 256 * 512);          // scan block sums (<=64)
    ushort* wts[4] = {wt0, wt1, wt2, wt3};

    const int nblk_scan = (n + 1023) / 1024;          // 20

    // ---- graph prep ----
    k_zero_int<<<(n + 255) / 256, 256, 0, stream>>>(cnt, n);
    k_count<<<(E + 255) / 256, 256, 0, stream>>>(e_col, cnt, E);
    k_scan_a<<<nblk_scan, 256, 0, stream>>>(cnt, rowptr, bsum, n);
    k_scan_b<<<1, 64, 0, stream>>>(bsum, rowptr, n, nblk_scan);
    k_scan_c<<<(n + 255) / 256, 256, 0, stream>>>(cnt, rowptr, cursor, deg, dinv, bsum, n);
    k_fill<<<(E + 255) / 256, 256, 0, stream>>>(e_row, e_col, dinv, cursor, csr_src, csr_w, E);

    // ---- weight transpose/convert (one kernel, all 4 layers) ----
    k_wt_all<<<(173056 + 255) / 256, 256, 0, stream>>>(W[0], W[1], W[2], W[3],
                                                       wt0, wt1, wt2, wt3);

    // ---- layer 1: fp32 agg -> bf16, then MFMA GEMM -> bf16 h ----
    {
        int K = 16, M = n, Nd = 64;
        int gpb = 256 >> 2;   // 64 nodes / block
        k_agg_pre_f32<<<(n + gpb - 1) / gpb, 256, 0, stream>>>(
            (const float4*)x, (ushort4*)bufB, rowptr, csr_src, csr_w, deg, dinv, n);
        dim3 ggrid((Nd + GBN - 1) / GBN, (M + GBM - 1) / GBM);
        gemm_mfma<<<ggrid, 256, 0, stream>>>(bufB, wts[0], b[0], bufA, M, K, Nd, 1);
    }

    // ---- layers 2..4: bf16 agg -> MFMA GEMM -> bf16 h ----
    for (int l = 1; l < 4; l++) {
        int K = dims[l], M = n, Nd = dims[l + 1];
        int g_shift = (K == 64) ? 3 : (K == 128) ? 4 : 5;   // lanes/node = K/8
        int gpb = 256 >> g_shift;
        k_agg_pre_bf16<<<(n + gpb - 1) / gpb, 256, 0, stream>>>(
            (const short8*)bufA, (short8*)bufB, rowptr, csr_src, csr_w, deg, dinv, n, g_shift);
        dim3 ggrid((Nd + GBN - 1) / GBN, (M + GBM - 1) / GBM);
        gemm_mfma<<<ggrid, 256, 0, stream>>>(bufB, wts[l], b[l], bufA, M, K, Nd, 1);
    }

    // ---- layer 5: bf16 dot + add-aggregate + sigmoid ----
    k_dot512_bf16<<<(n * 64 + 255) / 256, 256, 0, stream>>>(
        (const short8*)bufA, (const float4*)W[4], bufB_f, n);
    k_agg_final<<<(n + 255) / 256, 256, 0, stream>>>(bufB_f, (float*)d_out, rowptr,
                                                     csr_src, csr_w, dinv, b[4], n);
}

// Round 10
// 254.300 us; speedup vs baseline: 2.5426x; 1.0067x over previous
//
#include <hip/hip_runtime.h>
#include <hip/hip_bf16.h>
#include <math.h>

// GCN 5-layer: dims 16->64->128->256->512->1, N=20000, E=320000.
// Round 9: round-5 measured-good base (agg unroll-4, GEMM GBK=32/LDSS=40)
// + only the trivially-safe launch-diet changes from r6: k_prep0 fuses
// cnt-zero + weight transposes; scan_b folded into scan_c. The r6 suspects
// (agg unroll-8, GBK=64) are dropped to discriminate infra vs source after
// three consecutive container failures.

#define N_NODES 20000
#define N_EDGES 320000

typedef __attribute__((ext_vector_type(8))) short short8;
typedef __attribute__((ext_vector_type(4))) float f32x4;

__device__ inline ushort f2bf(float f) {
    __hip_bfloat16 h = __float2bfloat16(f);   // RNE
    return *(ushort*)&h;
}

__device__ inline float bf2f(short s) {
    union { unsigned int u; float f; } c;
    c.u = ((unsigned int)(unsigned short)s) << 16;
    return c.f;
}

// ---------------- prep0: zero cnt + all weight transposes (independent) -----
// wt segments (N*K): 1024, 8192, 32768, 131072 -> total 173056

__global__ void k_prep0(int* __restrict__ cnt, int n,
                        const float* __restrict__ W0, const float* __restrict__ W1,
                        const float* __restrict__ W2, const float* __restrict__ W3,
                        ushort* __restrict__ T0, ushort* __restrict__ T1,
                        ushort* __restrict__ T2, ushort* __restrict__ T3) {
    int i = blockIdx.x * blockDim.x + threadIdx.x;
    if (i < n) cnt[i] = 0;
    const float* W; ushort* T; int K, N, j;
    if (i < 1024)        { W = W0; T = T0; K = 16;  N = 64;  j = i; }
    else if (i < 9216)   { W = W1; T = T1; K = 64;  N = 128; j = i - 1024; }
    else if (i < 41984)  { W = W2; T = T2; K = 128; N = 256; j = i - 9216; }
    else if (i < 173056) { W = W3; T = T3; K = 256; N = 512; j = i - 41984; }
    else return;
    int nn = j / K, kk = j - nn * K;
    T[(size_t)nn * K + kk] = f2bf(W[(size_t)kk * N + nn]);
}

__global__ void k_count(const int* __restrict__ col, int* __restrict__ cnt, int E) {
    int e = blockIdx.x * blockDim.x + threadIdx.x;
    if (e < E) atomicAdd(&cnt[col[e]], 1);
}

// Phase A: 1024 elems/block, block-local exclusive prefix + block total.
__global__ __launch_bounds__(256) void k_scan_a(const int* __restrict__ cnt,
                                                int* __restrict__ rowptr,
                                                int* __restrict__ bsum, int n) {
    __shared__ int s[256];
    int b = blockIdx.x, tid = threadIdx.x;
    int base = b * 1024 + tid * 4;
    int v0 = 0, v1 = 0, v2 = 0, v3 = 0;
    if (base + 3 < n) {
        int4 c = *(const int4*)(cnt + base);
        v0 = c.x; v1 = c.y; v2 = c.z; v3 = c.w;
    } else {
        if (base < n)     v0 = cnt[base];
        if (base + 1 < n) v1 = cnt[base + 1];
        if (base + 2 < n) v2 = cnt[base + 2];
        if (base + 3 < n) v3 = cnt[base + 3];
    }
    s[tid] = v0 + v1 + v2 + v3;
    __syncthreads();
    for (int off = 1; off < 256; off <<= 1) {
        int x = s[tid];
        int add = (tid >= off) ? s[tid - off] : 0;
        __syncthreads();
        s[tid] = x + add;
        __syncthreads();
    }
    int excl = (tid == 0) ? 0 : s[tid - 1];
    if (base < n)     rowptr[base]     = excl;
    if (base + 1 < n) rowptr[base + 1] = excl + v0;
    if (base + 2 < n) rowptr[base + 2] = excl + v0 + v1;
    if (base + 3 < n) rowptr[base + 3] = excl + v0 + v1 + v2;
    if (tid == 255) bsum[b] = s[255];
}

// Phase C (scan_b folded in): each thread serially prefixes the <=20 block
// sums (broadcast L2 reads), adds its offset, emits cursor/deg/dinv.
__global__ void k_scan_c(const int* __restrict__ cnt, int* __restrict__ rowptr,
                         int* __restrict__ cursor, float* __restrict__ deg,
                         float* __restrict__ dinv, const int* __restrict__ bsum,
                         int n, int nblk) {
    int i = blockIdx.x * blockDim.x + threadIdx.x;
    if (i == 0) {
        int tot = 0;
        for (int j = 0; j < nblk; j++) tot += bsum[j];
        rowptr[n] = tot;
    }
    if (i >= n) return;
    int myblk = i >> 10;
    int off = 0;
    for (int j = 0; j < myblk; j++) off += bsum[j];
    int r = rowptr[i] + off;
    rowptr[i] = r;
    cursor[i] = r;
    int c = cnt[i];
    float d = (float)(c + 1);      // in-degree + self-loop
    deg[i] = d;
    dinv[i] = rsqrtf(d);
}

__global__ void k_fill(const int* __restrict__ row, const int* __restrict__ col,
                       const float* __restrict__ dinv, int* __restrict__ cursor,
                       int* __restrict__ csr_src, float* __restrict__ csr_w, int E) {
    int e = blockIdx.x * blockDim.x + threadIdx.x;
    if (e >= E) return;
    int s = row[e], d = col[e];
    int pos = atomicAdd(&cursor[d], 1);
    csr_src[pos] = s;
    csr_w[pos] = dinv[s] * dinv[d];
}

// ---------------- layer-1 pre-aggregation (fp32 x -> bf16 out), d=16 --------

__global__ void k_agg_pre_f32(const float4* __restrict__ h, ushort4* __restrict__ out,
                              const int* __restrict__ rowptr, const int* __restrict__ csr_src,
                              const float* __restrict__ csr_w, const float* __restrict__ deg,
                              const float* __restrict__ dinv, int n) {
    const int g_shift = 2;                       // d=16 -> 4 float4 lanes per node
    int g = 1 << g_shift;
    int grp = threadIdx.x >> g_shift;
    int lane = threadIdx.x & (g - 1);
    int gpb = blockDim.x >> g_shift;
    int v = blockIdx.x * gpb + grp;
    if (v >= n) return;
    float dv = dinv[v];
    float selfw = dv * dv;
    float inv_cnt = 1.0f / deg[v];
    int start = rowptr[v], end = rowptr[v + 1];
    float4 hv = h[(size_t)v * g + lane];
    float4 acc = make_float4(selfw * hv.x, selfw * hv.y, selfw * hv.z, selfw * hv.w);
    int e = start;
    for (; e + 4 <= end; e += 4) {
        int s0 = csr_src[e], s1 = csr_src[e + 1], s2 = csr_src[e + 2], s3 = csr_src[e + 3];
        float4 h0 = h[(size_t)s0 * g + lane];
        float4 h1 = h[(size_t)s1 * g + lane];
        float4 h2 = h[(size_t)s2 * g + lane];
        float4 h3 = h[(size_t)s3 * g + lane];
        float w0 = csr_w[e], w1 = csr_w[e + 1], w2 = csr_w[e + 2], w3 = csr_w[e + 3];
        acc.x += w0 * h0.x + w1 * h1.x + w2 * h2.x + w3 * h3.x;
        acc.y += w0 * h0.y + w1 * h1.y + w2 * h2.y + w3 * h3.y;
        acc.z += w0 * h0.z + w1 * h1.z + w2 * h2.z + w3 * h3.z;
        acc.w += w0 * h0.w + w1 * h1.w + w2 * h2.w + w3 * h3.w;
    }
    for (; e < end; e++) {
        int s = csr_src[e];
        float w = csr_w[e];
        float4 hs = h[(size_t)s * g + lane];
        acc.x += w * hs.x; acc.y += w * hs.y; acc.z += w * hs.z; acc.w += w * hs.w;
    }
    ushort4 o;
    o.x = f2bf(acc.x * inv_cnt);
    o.y = f2bf(acc.y * inv_cnt);
    o.z = f2bf(acc.z * inv_cnt);
    o.w = f2bf(acc.w * inv_cnt);
    out[(size_t)v * g + lane] = o;
}

// ---------------- bf16 pre-aggregation (layers 2..4), unroll-4 MLP ----------

__global__ void k_agg_pre_bf16(const short8* __restrict__ h, short8* __restrict__ out,
                               const int* __restrict__ rowptr, const int* __restrict__ csr_src,
                               const float* __restrict__ csr_w, const float* __restrict__ deg,
                               const float* __restrict__ dinv, int n, int g_shift) {
    int g = 1 << g_shift;                        // lanes per node = d/8
    int grp = threadIdx.x >> g_shift;
    int lane = threadIdx.x & (g - 1);
    int gpb = blockDim.x >> g_shift;
    int v = blockIdx.x * gpb + grp;
    if (v >= n) return;
    float dv = dinv[v];
    float selfw = dv * dv;
    float inv_cnt = 1.0f / deg[v];
    int start = rowptr[v], end = rowptr[v + 1];

    float acc[8];
    short8 hv = h[(size_t)v * g + lane];
    #pragma unroll
    for (int i = 0; i < 8; i++) acc[i] = selfw * bf2f(hv[i]);

    int e = start;
    for (; e + 4 <= end; e += 4) {
        int s0 = csr_src[e], s1 = csr_src[e + 1], s2 = csr_src[e + 2], s3 = csr_src[e + 3];
        short8 h0 = h[(size_t)s0 * g + lane];
        short8 h1 = h[(size_t)s1 * g + lane];
        short8 h2 = h[(size_t)s2 * g + lane];
        short8 h3 = h[(size_t)s3 * g + lane];
        float w0 = csr_w[e], w1 = csr_w[e + 1], w2 = csr_w[e + 2], w3 = csr_w[e + 3];
        #pragma unroll
        for (int i = 0; i < 8; i++)
            acc[i] += w0 * bf2f(h0[i]) + w1 * bf2f(h1[i])
                    + w2 * bf2f(h2[i]) + w3 * bf2f(h3[i]);
    }
    for (; e < end; e++) {
        int s0 = csr_src[e];
        float w0 = csr_w[e];
        short8 h0 = h[(size_t)s0 * g + lane];
        #pragma unroll
        for (int i = 0; i < 8; i++) acc[i] += w0 * bf2f(h0[i]);
    }
    short8 o;
    #pragma unroll
    for (int i = 0; i < 8; i++) o[i] = (short)f2bf(acc[i] * inv_cnt);
    out[(size_t)v * g + lane] = o;
}

// ---------------- MFMA GEMM: C_bf16[M,N] = relu(A[M,K] @ Wt[N,K]^T + bias) --
// bf16 in/out, fp32 accumulate. 128x128 tile, 4 waves, 4x4 16x16x32 MFMAs.

#define GBM 128
#define GBN 128
#define GBK 32
#define LDSS 40   // LDS row stride in elements (80B, 16B-aligned)

__global__ __launch_bounds__(256) void gemm_mfma(const ushort* __restrict__ A,
                                                 const ushort* __restrict__ Wt,
                                                 const float* __restrict__ bias,
                                                 ushort* __restrict__ C,
                                                 int M, int K, int N, int do_relu) {
    __shared__ ushort As[GBM * LDSS];
    __shared__ ushort Bs[GBN * LDSS];
    int tid = threadIdx.x;
    int wave = tid >> 6;
    int lane = tid & 63;
    int wr = wave >> 1, wc = wave & 1;
    int q = lane >> 4;          // quad 0..3
    int mr = lane & 15;
    int row0 = blockIdx.y * GBM;
    int col0 = blockIdx.x * GBN;

    f32x4 acc[4][4];
    #pragma unroll
    for (int i = 0; i < 4; i++)
        #pragma unroll
        for (int j = 0; j < 4; j++) acc[i][j] = (f32x4){0.f, 0.f, 0.f, 0.f};

    const short8 zero8 = {0, 0, 0, 0, 0, 0, 0, 0};

    for (int k0 = 0; k0 < K; k0 += GBK) {
        #pragma unroll
        for (int it = 0; it < 2; it++) {
            int t = tid + it * 256;
            int r = t >> 2;               // row in tile (0..127)
            int koff = (t & 3) * 8;       // k offset in tile
            int gk = k0 + koff;
            short8 va = zero8;
            int gr = row0 + r;
            if (gr < M && gk < K)
                va = *(const short8*)(A + (size_t)gr * K + gk);
            *(short8*)(As + r * LDSS + koff) = va;
            short8 vb = zero8;
            int gn = col0 + r;
            if (gn < N && gk < K)
                vb = *(const short8*)(Wt + (size_t)gn * K + gk);
            *(short8*)(Bs + r * LDSS + koff) = vb;
        }
        __syncthreads();
        short8 afr[4], bfr[4];
        #pragma unroll
        for (int i = 0; i < 4; i++)
            afr[i] = *(const short8*)(As + (wr * 64 + i * 16 + mr) * LDSS + q * 8);
        #pragma unroll
        for (int j = 0; j < 4; j++)
            bfr[j] = *(const short8*)(Bs + (wc * 64 + j * 16 + mr) * LDSS + q * 8);
        #pragma unroll
        for (int i = 0; i < 4; i++)
            #pragma unroll
            for (int j = 0; j < 4; j++)
                acc[i][j] = __builtin_amdgcn_mfma_f32_16x16x32_bf16(afr[i], bfr[j],
                                                                    acc[i][j], 0, 0, 0);
        __syncthreads();
    }

    // epilogue: C/D layout col=lane&15, row=q*4+reg; emit bf16
    #pragma unroll
    for (int j = 0; j < 4; j++) {
        int col = col0 + wc * 64 + j * 16 + mr;
        if (col >= N) continue;
        float bj = bias[col];
        #pragma unroll
        for (int i = 0; i < 4; i++) {
            int rbase = row0 + wr * 64 + i * 16 + q * 4;
            #pragma unroll
            for (int r = 0; r < 4; r++) {
                int grow = rbase + r;
                if (grow < M) {
                    float v = acc[i][j][r] + bj;
                    if (do_relu) v = fmaxf(v, 0.0f);
                    C[(size_t)grow * N + col] = f2bf(v);
                }
            }
        }
    }
}

// ---------------- final layer ----------------

__global__ void k_dot512_bf16(const short8* __restrict__ A, const float4* __restrict__ w,
                              float* __restrict__ out, int n) {
    int wv = (blockIdx.x * blockDim.x + threadIdx.x) >> 6;
    int lane = threadIdx.x & 63;
    if (wv >= n) return;
    short8 a = A[(size_t)wv * 64 + lane];
    float4 w0 = w[lane * 2], w1 = w[lane * 2 + 1];
    float acc = bf2f(a[0]) * w0.x + bf2f(a[1]) * w0.y + bf2f(a[2]) * w0.z + bf2f(a[3]) * w0.w
              + bf2f(a[4]) * w1.x + bf2f(a[5]) * w1.y + bf2f(a[6]) * w1.z + bf2f(a[7]) * w1.w;
    #pragma unroll
    for (int off = 32; off > 0; off >>= 1) acc += __shfl_down(acc, off, 64);
    if (lane == 0) out[wv] = acc;
}

__global__ void k_agg_final(const float* __restrict__ h, float* __restrict__ out,
                            const int* __restrict__ rowptr, const int* __restrict__ csr_src,
                            const float* __restrict__ csr_w, const float* __restrict__ dinv,
                            const float* __restrict__ b5, int n) {
    int v = blockIdx.x * blockDim.x + threadIdx.x;
    if (v >= n) return;
    float acc = dinv[v] * dinv[v] * h[v];
    int end = rowptr[v + 1];
    for (int e = rowptr[v]; e < end; e++) acc += csr_w[e] * h[csr_src[e]];
    float r = acc + b5[0];                 // 'add' aggregation (output layer)
    out[v] = 1.0f / (1.0f + expf(-r));     // sigmoid
}

// ---------------- launch ----------------

extern "C" void kernel_launch(void* const* d_in, const int* in_sizes, int n_in,
                              void* d_out, int out_size, void* d_ws, size_t ws_size,
                              hipStream_t stream) {
    const float* x   = (const float*)d_in[0];
    const int*   ei  = (const int*)d_in[1];
    const float* W[5] = {(const float*)d_in[2], (const float*)d_in[4], (const float*)d_in[6],
                         (const float*)d_in[8], (const float*)d_in[10]};
    const float* b[5] = {(const float*)d_in[3], (const float*)d_in[5], (const float*)d_in[7],
                         (const float*)d_in[9], (const float*)d_in[11]};
    const int n = in_sizes[0] / 16;
    const int E = in_sizes[1] / 2;
    const int dims[6] = {16, 64, 128, 256, 512, 1};

    const int* e_row = ei;          // src
    const int* e_col = ei + E;      // dst

    // workspace layout
    float* bufA_f = (float*)d_ws;                     // n*512 floats region
    float* bufB_f = bufA_f + (size_t)n * 512;         // n*512 floats region
    ushort* bufA  = (ushort*)bufA_f;                  // h (GEMM out, bf16)
    ushort* bufB  = (ushort*)bufB_f;                  // agg out (bf16)
    int*   cnt    = (int*)(bufB_f + (size_t)n * 512); // n
    int*   rowptr = cnt + n;                          // n+1 (pad to n+4)
    int*   cursor = rowptr + n + 4;                   // n
    float* deg    = (float*)(cursor + n);             // n
    float* dinv   = deg + n;                          // n
    int*   csr_src= (int*)(dinv + n);                 // E
    float* csr_w  = (float*)(csr_src + E);            // E
    ushort* wt0   = (ushort*)(csr_w + E);             // bf16 transposed weights
    ushort* wt1   = wt0 + 16 * 64;
    ushort* wt2   = wt1 + 64 * 128;
    ushort* wt3   = wt2 + 128 * 256;
    int*   bsum   = (int*)(wt3 + 256 * 512);          // scan block sums (<=64)
    ushort* wts[4] = {wt0, wt1, wt2, wt3};

    const int nblk_scan = (n + 1023) / 1024;          // 20

    // ---- graph prep ----
    k_prep0<<<(173056 + 255) / 256, 256, 0, stream>>>(cnt, n, W[0], W[1], W[2], W[3],
                                                      wt0, wt1, wt2, wt3);
    k_count<<<(E + 255) / 256, 256, 0, stream>>>(e_col, cnt, E);
    k_scan_a<<<nblk_scan, 256, 0, stream>>>(cnt, rowptr, bsum, n);
    k_scan_c<<<(n + 255) / 256, 256, 0, stream>>>(cnt, rowptr, cursor, deg, dinv,
                                                  bsum, n, nblk_scan);
    k_fill<<<(E + 255) / 256, 256, 0, stream>>>(e_row, e_col, dinv, cursor, csr_src, csr_w, E);

    // ---- layer 1: fp32 agg -> bf16, then MFMA GEMM -> bf16 h ----
    {
        int K = 16, M = n, Nd = 64;
        int gpb = 256 >> 2;   // 64 nodes / block
        k_agg_pre_f32<<<(n + gpb - 1) / gpb, 256, 0, stream>>>(
            (const float4*)x, (ushort4*)bufB, rowptr, csr_src, csr_w, deg, dinv, n);
        dim3 ggrid((Nd + GBN - 1) / GBN, (M + GBM - 1) / GBM);
        gemm_mfma<<<ggrid, 256, 0, stream>>>(bufB, wts[0], b[0], bufA, M, K, Nd, 1);
    }

    // ---- layers 2..4: bf16 agg -> MFMA GEMM -> bf16 h ----
    for (int l = 1; l < 4; l++) {
        int K = dims[l], M = n, Nd = dims[l + 1];
        int g_shift = (K == 64) ? 3 : (K == 128) ? 4 : 5;   // lanes/node = K/8
        int gpb = 256 >> g_shift;
        k_agg_pre_bf16<<<(n + gpb - 1) / gpb, 256, 0, stream>>>(
            (const short8*)bufA, (short8*)bufB, rowptr, csr_src, csr_w, deg, dinv, n, g_shift);
        dim3 ggrid((Nd + GBN - 1) / GBN, (M + GBM - 1) / GBM);
        gemm_mfma<<<ggrid, 256, 0, stream>>>(bufB, wts[l], b[l], bufA, M, K, Nd, 1);
    }

    // ---- layer 5: bf16 dot + add-aggregate + sigmoid ----
    k_dot512_bf16<<<(n * 64 + 255) / 256, 256, 0, stream>>>(
        (const short8*)bufA, (const float4*)W[4], bufB_f, n);
    k_agg_final<<<(n + 255) / 256, 256, 0, stream>>>(bufB_f, (float*)d_out, rowptr,
                                                     csr_src, csr_w, dinv, b[4], n);
}